// Round 1
// baseline (5088.618 us; speedup 1.0000x reference)
//
#include <hip/hip_runtime.h>
#include <hip/hip_bf16.h>
#include <math.h>

#define N_NODES 100000
#define R_REL 3
#define E_EDGES 320000
#define HID 128
#define HD 128
#define NBLK 391   // ceil(N/256)

// ---------------- workspace layout (byte offsets, all 256B aligned) ----------------
static constexpr size_t OFF_DSTT  = 0;                     // N*128 f32        = 51,200,000 B
static constexpr size_t OFF_B1    = 51200000;              // srcT / z_r: R*N*128 f32 = 153,600,000 B
static constexpr size_t OFF_B2    = 204800000;             // hs / T: R*N*128 f32     = 153,600,000 B
static constexpr size_t OFF_EL    = 358400000;             // R*N*4 f32 = 4,800,000 B
static constexpr size_t OFF_ER    = 363200000;             // R*N*4 f32 = 4,800,000 B
static constexpr size_t OFF_WREFF = 368000000;             // R*128*4 f32 = 6,144 B
static constexpr size_t OFF_CNT   = 368006144;             // R*N i32 = 1,200,000 B
static constexpr size_t OFF_OFFS  = 369206144;             // R*(N+1) i32 -> 1,200,128 B padded
static constexpr size_t OFF_CUR   = 370406272;             // R*N i32 = 1,200,000 B
static constexpr size_t OFF_BSUM  = 371606272;             // R*NBLK i32 -> 4,864 B
static constexpr size_t OFF_BOFF  = 371611136;             // R*NBLK i32 -> 4,864 B
static constexpr size_t OFF_CSR   = 371616000;             // R*E i32 = 3,840,000 B
static constexpr size_t OFF_WSUM  = 375456000;             // 3 f32 (+pad)
static constexpr size_t OFF_ABUF  = 375456064;             // 3 f32

// ---------------- fp32 GEMM: C[M,128] = A[M,128] @ B[128,128] (+bias) ----------------
// batched over gridDim.y with byte-free (element) strides.
__global__ __launch_bounds__(256) void gemm128(
    const float* __restrict__ A, long long sAb,
    const float* __restrict__ B, long long sBb,
    const float* __restrict__ bias, long long sbias, int has_bias,
    float* __restrict__ C, long long sCb, int M)
{
    constexpr int KC = 32;
    constexpr int PITCH = 132;   // 16B-aligned rows (132*4=528)
    __shared__ float As[KC * PITCH];   // As[kk][row] (transposed)
    __shared__ float Bs[KC * PITCH];   // Bs[kk][col]
    const int bz = blockIdx.y;
    A += (long long)bz * sAb;
    B += (long long)bz * sBb;
    C += (long long)bz * sCb;
    if (has_bias) bias += (long long)bz * sbias;

    const int t  = threadIdx.x;
    const int tx = t & 15;      // col group
    const int ty = t >> 4;      // row group
    const int row0 = blockIdx.x * 128;

    float acc[8][8];
#pragma unroll
    for (int i = 0; i < 8; ++i)
#pragma unroll
        for (int j = 0; j < 8; ++j) acc[i][j] = 0.0f;

    for (int kc = 0; kc < 128; kc += KC) {
        __syncthreads();
        // stage A chunk (128 rows x 32 k), transposed into As[kk][row]
#pragma unroll
        for (int i = 0; i < 4; ++i) {
            int idx = t + i * 256;          // 1024 float4
            int r   = idx >> 3;             // 8 float4 per row
            int kq  = idx & 7;
            int gr  = row0 + r; gr = (gr < M) ? gr : (M - 1);
            const float4 v = *(const float4*)(A + (long long)gr * HID + kc + kq * 4);
            As[(kq * 4 + 0) * PITCH + r] = v.x;
            As[(kq * 4 + 1) * PITCH + r] = v.y;
            As[(kq * 4 + 2) * PITCH + r] = v.z;
            As[(kq * 4 + 3) * PITCH + r] = v.w;
        }
        // stage B chunk (32 k x 128 cols), natural layout
#pragma unroll
        for (int i = 0; i < 4; ++i) {
            int idx = t + i * 256;
            int k   = idx >> 5;             // 32 float4 per row
            int c4  = idx & 31;
            const float4 v = *(const float4*)(B + (long long)(kc + k) * HID + c4 * 4);
            *(float4*)(&Bs[k * PITCH + c4 * 4]) = v;
        }
        __syncthreads();
#pragma unroll
        for (int kk = 0; kk < KC; ++kk) {
            float a[8], bb[8];
            const float* Ap = &As[kk * PITCH + ty * 8];
            const float* Bp = &Bs[kk * PITCH + tx * 8];
            *(float4*)&a[0]  = *(const float4*)(Ap);
            *(float4*)&a[4]  = *(const float4*)(Ap + 4);
            *(float4*)&bb[0] = *(const float4*)(Bp);
            *(float4*)&bb[4] = *(const float4*)(Bp + 4);
#pragma unroll
            for (int ri = 0; ri < 8; ++ri)
#pragma unroll
                for (int ci = 0; ci < 8; ++ci)
                    acc[ri][ci] += a[ri] * bb[ci];
        }
    }

    float bv[8];
#pragma unroll
    for (int ci = 0; ci < 8; ++ci) bv[ci] = has_bias ? bias[tx * 8 + ci] : 0.0f;

#pragma unroll
    for (int ri = 0; ri < 8; ++ri) {
        int gr = row0 + ty * 8 + ri;
        if (gr < M) {
            float4 o0 = { acc[ri][0] + bv[0], acc[ri][1] + bv[1], acc[ri][2] + bv[2], acc[ri][3] + bv[3] };
            float4 o1 = { acc[ri][4] + bv[4], acc[ri][5] + bv[5], acc[ri][6] + bv[6], acc[ri][7] + bv[7] };
            *(float4*)(C + (long long)gr * HID + tx * 8)     = o0;
            *(float4*)(C + (long long)gr * HID + tx * 8 + 4) = o1;
        }
    }
}

// ---------------- wr_eff[r][f][h] = sum_d Wg[r][f][h*32+d] * attn_r[r][h*32+d] ----------------
__global__ void wreff_kernel(const float* __restrict__ Wg, const float* __restrict__ attn_r,
                             float* __restrict__ wreff)
{
    int tid = blockIdx.x * 256 + threadIdx.x;
    if (tid >= R_REL * 128 * 4) return;
    int r = tid >> 9;
    int f = (tid >> 2) & 127;
    int h = tid & 3;
    float s = 0.0f;
#pragma unroll
    for (int d = 0; d < 32; ++d)
        s += Wg[r * 16384 + f * 128 + h * 32 + d] * attn_r[r * 128 + h * 32 + d];
    wreff[tid] = s;
}

// ---------------- er[r][n][h] = dstT[n,:] @ wr_eff[r][:,h] ; one wave per (r,n) ----------------
__global__ __launch_bounds__(256) void er_kernel(const float* __restrict__ dstT,
                                                 const float* __restrict__ wreff,
                                                 float* __restrict__ er)
{
    int gid = blockIdx.x * 4 + (threadIdx.x >> 6);
    int r = gid / N_NODES, n = gid - r * N_NODES;
    int lane = threadIdx.x & 63;
    float d0 = dstT[(size_t)n * HID + lane];
    float d1 = dstT[(size_t)n * HID + 64 + lane];
    float4 w0 = *(const float4*)(wreff + r * 512 + lane * 4);
    float4 w1 = *(const float4*)(wreff + r * 512 + (64 + lane) * 4);
    float p0 = d0 * w0.x + d1 * w1.x;
    float p1 = d0 * w0.y + d1 * w1.y;
    float p2 = d0 * w0.z + d1 * w1.z;
    float p3 = d0 * w0.w + d1 * w1.w;
#pragma unroll
    for (int off = 32; off >= 1; off >>= 1) {
        p0 += __shfl_down(p0, off);
        p1 += __shfl_down(p1, off);
        p2 += __shfl_down(p2, off);
        p3 += __shfl_down(p3, off);
    }
    if (lane == 0) {
        float4 o = { p0, p1, p2, p3 };
        *(float4*)(er + (size_t)gid * 4) = o;
    }
}

// ---------------- el[r][n][h] = sum_d hs[r][n][h*32+d] * attn_l[r][h*32+d] ----------------
__global__ __launch_bounds__(256) void el_kernel(const float* __restrict__ hs,
                                                 const float* __restrict__ attn_l,
                                                 float* __restrict__ el)
{
    int gid = blockIdx.x * 2 + (threadIdx.x >> 7);
    int r = gid / N_NODES;
    int c = threadIdx.x & 127;
    float v = hs[(size_t)gid * HD + c] * attn_l[r * HD + c];
    v += __shfl_down(v, 16, 32);
    v += __shfl_down(v, 8, 32);
    v += __shfl_down(v, 4, 32);
    v += __shfl_down(v, 2, 32);
    v += __shfl_down(v, 1, 32);
    if ((c & 31) == 0) el[(size_t)gid * 4 + (c >> 5)] = v;
}

// ---------------- CSR build ----------------
__global__ void count_kernel(const int* __restrict__ dst_idx, int* __restrict__ counts)
{
    int tid = blockIdx.x * 256 + threadIdx.x;
    if (tid >= R_REL * E_EDGES) return;
    int r = tid / E_EDGES;
    atomicAdd(&counts[r * N_NODES + dst_idx[tid]], 1);
}

__global__ void blocksum_kernel(const int* __restrict__ counts, int* __restrict__ bsums)
{
    int r = blockIdx.y;
    int i = blockIdx.x * 256 + threadIdx.x;
    int v = (i < N_NODES) ? counts[r * N_NODES + i] : 0;
#pragma unroll
    for (int off = 32; off >= 1; off >>= 1) v += __shfl_down(v, off);
    __shared__ int wsum[4];
    int lane = threadIdx.x & 63, w = threadIdx.x >> 6;
    if (lane == 0) wsum[w] = v;
    __syncthreads();
    if (threadIdx.x == 0) bsums[r * NBLK + blockIdx.x] = wsum[0] + wsum[1] + wsum[2] + wsum[3];
}

__global__ void scan_bsums(const int* __restrict__ bsums, int* __restrict__ boffs,
                           int* __restrict__ offs)
{
    int r = blockIdx.x;
    if (threadIdx.x != 0) return;
    int run = 0;
    for (int b = 0; b < NBLK; ++b) { boffs[r * NBLK + b] = run; run += bsums[r * NBLK + b]; }
    offs[r * (N_NODES + 1) + N_NODES] = run;
}

__global__ void scan_final(const int* __restrict__ counts, const int* __restrict__ boffs,
                           int* __restrict__ offs, int* __restrict__ cursor)
{
    int r = blockIdx.y;
    int i = blockIdx.x * 256 + threadIdx.x;
    int t = threadIdx.x;
    int v = (i < N_NODES) ? counts[r * N_NODES + i] : 0;
    __shared__ int sd[256];
    sd[t] = v;
    __syncthreads();
    for (int off = 1; off < 256; off <<= 1) {
        int y = (t >= off) ? sd[t - off] : 0;
        __syncthreads();
        sd[t] += y;
        __syncthreads();
    }
    int excl = sd[t] - v + boffs[r * NBLK + blockIdx.x];
    if (i < N_NODES) {
        offs[r * (N_NODES + 1) + i] = excl;
        cursor[r * N_NODES + i] = excl;
    }
}

__global__ void scatter_kernel(const int* __restrict__ src_idx, const int* __restrict__ dst_idx,
                               int* __restrict__ cursor, int* __restrict__ csr_src)
{
    int tid = blockIdx.x * 256 + threadIdx.x;
    if (tid >= R_REL * E_EDGES) return;
    int r = tid / E_EDGES;
    int pos = atomicAdd(&cursor[r * N_NODES + dst_idx[tid]], 1);
    csr_src[r * E_EDGES + pos] = src_idx[tid];
}

// ---------------- node-centric GAT aggregation: one wave per (r,n) ----------------
__global__ __launch_bounds__(256) void agg_kernel(
    const float* __restrict__ el, const float* __restrict__ er,
    const float* __restrict__ hs, const int* __restrict__ offs,
    const int* __restrict__ csr_src, const float* __restrict__ bias_g,
    float* __restrict__ zr)
{
    int wid = blockIdx.x * 4 + (threadIdx.x >> 6);
    int r = wid / N_NODES, n = wid - r * N_NODES;
    int lane = threadIdx.x & 63;
    int h0 = lane >> 5;                 // head of col c0 (0/1); head of c1 is h0+2
    int c0 = lane, c1 = lane + 64;

    const float4 er4 = *(const float4*)(er + (size_t)wid * 4);
    float er0 = h0 ? er4.y : er4.x;
    float er1 = h0 ? er4.w : er4.z;

    int beg = offs[r * (N_NODES + 1) + n];
    int end = offs[r * (N_NODES + 1) + n + 1];
    const int*   srcs = csr_src + (size_t)r * E_EDGES;
    const float* elr  = el + (size_t)r * N_NODES * 4;
    const float* hsr  = hs + (size_t)r * N_NODES * HD;

    float m0 = -INFINITY, m1 = -INFINITY;
    for (int j = beg; j < end; ++j) {
        int s = srcs[j];
        float4 el4 = *(const float4*)(elr + (size_t)s * 4);
        float e0 = (h0 ? el4.y : el4.x) + er0;
        float e1 = (h0 ? el4.w : el4.z) + er1;
        e0 = e0 > 0.0f ? e0 : 0.2f * e0;
        e1 = e1 > 0.0f ? e1 : 0.2f * e1;
        m0 = fmaxf(m0, e0); m1 = fmaxf(m1, e1);
    }
    float ss0 = 0.0f, ss1 = 0.0f, acc0 = 0.0f, acc1 = 0.0f;
    for (int j = beg; j < end; ++j) {
        int s = srcs[j];
        float4 el4 = *(const float4*)(elr + (size_t)s * 4);
        float e0 = (h0 ? el4.y : el4.x) + er0;
        float e1 = (h0 ? el4.w : el4.z) + er1;
        e0 = e0 > 0.0f ? e0 : 0.2f * e0;
        e1 = e1 > 0.0f ? e1 : 0.2f * e1;
        float ex0 = __expf(e0 - m0), ex1 = __expf(e1 - m1);
        ss0 += ex0; ss1 += ex1;
        acc0 += ex0 * hsr[(size_t)s * HD + c0];
        acc1 += ex1 * hsr[(size_t)s * HD + c1];
    }
    float r0 = acc0 / (ss0 + 1e-9f) + bias_g[r * HD + c0];
    float r1 = acc1 / (ss1 + 1e-9f) + bias_g[r * HD + c1];
    r0 = r0 > 0.0f ? r0 : (__expf(r0) - 1.0f);   // elu
    r1 = r1 > 0.0f ? r1 : (__expf(r1) - 1.0f);
    zr[(size_t)wid * HD + c0] = r0;
    zr[(size_t)wid * HD + c1] = r1;
}

// ---------------- semantic attention ----------------
__global__ __launch_bounds__(256) void wsem_kernel(const float* __restrict__ T,
                                                   const float* __restrict__ W2,
                                                   float* __restrict__ wsum)
{
    int gid = blockIdx.x * 4 + (threadIdx.x >> 6);
    int r = gid / N_NODES;
    int lane = threadIdx.x & 63;
    float p = tanhf(T[(size_t)gid * 128 + lane]) * W2[lane]
            + tanhf(T[(size_t)gid * 128 + 64 + lane]) * W2[64 + lane];
#pragma unroll
    for (int off = 32; off >= 1; off >>= 1) p += __shfl_down(p, off);
    if (lane == 0) atomicAdd(&wsum[r], p);
}

__global__ void softmax_a(const float* __restrict__ wsum, float* __restrict__ a,
                          float* __restrict__ out)
{
    if (threadIdx.x == 0 && blockIdx.x == 0) {
        float w0 = wsum[0] / (float)N_NODES;
        float w1 = wsum[1] / (float)N_NODES;
        float w2 = wsum[2] / (float)N_NODES;
        float m = fmaxf(w0, fmaxf(w1, w2));
        float e0 = __expf(w0 - m), e1 = __expf(w1 - m), e2 = __expf(w2 - m);
        float s = e0 + e1 + e2;
        a[0] = e0 / s; a[1] = e1 / s; a[2] = e2 / s;
        out[(size_t)N_NODES * HD + 0] = a[0];
        out[(size_t)N_NODES * HD + 1] = a[1];
        out[(size_t)N_NODES * HD + 2] = a[2];
    }
}

__global__ __launch_bounds__(256) void combine_kernel(const float* __restrict__ zr,
                                                      const float* __restrict__ a,
                                                      float* __restrict__ out)
{
    size_t i = (size_t)blockIdx.x * 256 + threadIdx.x;   // float4 index, exact grid
    float a0 = a[0], a1 = a[1], a2 = a[2];
    const float4 v0 = ((const float4*)zr)[i];
    const float4 v1 = ((const float4*)(zr + (size_t)N_NODES * HD))[i];
    const float4 v2 = ((const float4*)(zr + 2 * (size_t)N_NODES * HD))[i];
    float4 o = { a0 * v0.x + a1 * v1.x + a2 * v2.x,
                 a0 * v0.y + a1 * v1.y + a2 * v2.y,
                 a0 * v0.z + a1 * v1.z + a2 * v2.z,
                 a0 * v0.w + a1 * v1.w + a2 * v2.w };
    ((float4*)out)[i] = o;
}

// ---------------- launch ----------------
extern "C" void kernel_launch(void* const* d_in, const int* in_sizes, int n_in,
                              void* d_out, int out_size, void* d_ws, size_t ws_size,
                              hipStream_t stream)
{
    const float* dst_feat  = (const float*)d_in[0];
    const float* src_feats = (const float*)d_in[1];
    const int*   src_idx   = (const int*)d_in[2];
    const int*   dst_idx   = (const int*)d_in[3];
    const float* Wt_dst    = (const float*)d_in[4];
    const float* bt_dst    = (const float*)d_in[5];
    const float* Wt_src    = (const float*)d_in[6];
    const float* bt_src    = (const float*)d_in[7];
    const float* Wg        = (const float*)d_in[8];
    const float* attn_l    = (const float*)d_in[9];
    const float* attn_r    = (const float*)d_in[10];
    const float* bias_g    = (const float*)d_in[11];
    const float* W1        = (const float*)d_in[12];
    const float* b1        = (const float*)d_in[13];
    const float* W2        = (const float*)d_in[14];
    float* out = (float*)d_out;

    char* ws = (char*)d_ws;
    float* dstT   = (float*)(ws + OFF_DSTT);
    float* srcT   = (float*)(ws + OFF_B1);    // later reused as z_r
    float* zr     = srcT;
    float* hs     = (float*)(ws + OFF_B2);    // later reused as T
    float* Tbuf   = hs;
    float* el     = (float*)(ws + OFF_EL);
    float* er     = (float*)(ws + OFF_ER);
    float* wreff  = (float*)(ws + OFF_WREFF);
    int*   counts = (int*)(ws + OFF_CNT);
    int*   offs   = (int*)(ws + OFF_OFFS);
    int*   cursor = (int*)(ws + OFF_CUR);
    int*   bsums  = (int*)(ws + OFF_BSUM);
    int*   boffs  = (int*)(ws + OFF_BOFF);
    int*   csr    = (int*)(ws + OFF_CSR);
    float* wsum   = (float*)(ws + OFF_WSUM);
    float* abuf   = (float*)(ws + OFF_ABUF);

    hipMemsetAsync(counts, 0, (size_t)R_REL * N_NODES * 4, stream);
    hipMemsetAsync(wsum, 0, 16, stream);

    // input projections
    gemm128<<<dim3(782, 1), 256, 0, stream>>>(dst_feat, 0, Wt_dst, 0, bt_dst, 0, 1,
                                              dstT, 0, N_NODES);
    gemm128<<<dim3(782, 3), 256, 0, stream>>>(src_feats, (long long)N_NODES * HID,
                                              Wt_src, 128 * 128, bt_src, 128, 1,
                                              srcT, (long long)N_NODES * HID, N_NODES);
    // hs = srcT @ Wg (no bias)
    gemm128<<<dim3(782, 3), 256, 0, stream>>>(srcT, (long long)N_NODES * HID,
                                              Wg, 128 * 128, nullptr, 0, 0,
                                              hs, (long long)N_NODES * HID, N_NODES);
    // attention logits
    wreff_kernel<<<6, 256, 0, stream>>>(Wg, attn_r, wreff);
    er_kernel<<<75000, 256, 0, stream>>>(dstT, wreff, er);
    el_kernel<<<150000, 256, 0, stream>>>(hs, attn_l, el);
    // CSR by dst
    count_kernel<<<3750, 256, 0, stream>>>(dst_idx, counts);
    blocksum_kernel<<<dim3(NBLK, 3), 256, 0, stream>>>(counts, bsums);
    scan_bsums<<<3, 64, 0, stream>>>(bsums, boffs, offs);
    scan_final<<<dim3(NBLK, 3), 256, 0, stream>>>(counts, boffs, offs, cursor);
    scatter_kernel<<<3750, 256, 0, stream>>>(src_idx, dst_idx, cursor, csr);
    // edge-softmax + aggregation (pull), writes z_r into B1 (srcT dead)
    agg_kernel<<<75000, 256, 0, stream>>>(el, er, hs, offs, csr, bias_g, zr);
    // semantic attention: T = Zm @ W1 + b1 into B2 (hs dead)
    gemm128<<<dim3(2344, 1), 256, 0, stream>>>(zr, 0, W1, 0, b1, 0, 1,
                                               Tbuf, 0, R_REL * N_NODES);
    wsem_kernel<<<75000, 256, 0, stream>>>(Tbuf, W2, wsum);
    softmax_a<<<1, 64, 0, stream>>>(wsum, abuf, out);
    combine_kernel<<<12500, 256, 0, stream>>>(zr, abuf, out);
}

// Round 2
// 1282.599 us; speedup vs baseline: 3.9674x; 3.9674x over previous
//
#include <hip/hip_runtime.h>
#include <hip/hip_bf16.h>
#include <math.h>

#define N_NODES 100000
#define R_REL 3
#define E_EDGES 320000
#define HID 128
#define HD 128
#define NBLK 391   // ceil(N/256)
#define WSEM_BLOCKS 200

// ---------------- workspace layout (byte offsets, all 256B aligned) ----------------
static constexpr size_t OFF_DSTT  = 0;                     // N*128 f32        = 51,200,000 B
static constexpr size_t OFF_B1    = 51200000;              // srcT / z_r: R*N*128 f32 = 153,600,000 B
static constexpr size_t OFF_B2    = 204800000;             // hs / T: R*N*128 f32     = 153,600,000 B
static constexpr size_t OFF_EL    = 358400000;             // R*N*4 f32 = 4,800,000 B
static constexpr size_t OFF_ER    = 363200000;             // R*N*4 f32 = 4,800,000 B
static constexpr size_t OFF_WREFF = 368000000;             // R*128*4 f32 = 6,144 B
static constexpr size_t OFF_CNT   = 368006144;             // R*N i32 = 1,200,000 B
static constexpr size_t OFF_OFFS  = 369206144;             // R*(N+1) i32 -> 1,200,128 B padded
static constexpr size_t OFF_CUR   = 370406272;             // R*N i32 = 1,200,000 B
static constexpr size_t OFF_BSUM  = 371606272;             // R*NBLK i32 -> 4,864 B
static constexpr size_t OFF_BOFF  = 371611136;             // R*NBLK i32 -> 4,864 B
static constexpr size_t OFF_CSR   = 371616000;             // R*E i32 = 3,840,000 B
static constexpr size_t OFF_ABUF  = 375456000;             // 3 f32 (+pad)
static constexpr size_t OFF_PART  = 375456256;             // R*WSEM_BLOCKS f32 = 2,400 B

// ---------------- fp32 GEMM: C[M,128] = A[M,128] @ B[128,128] (+bias) ----------------
__global__ __launch_bounds__(256) void gemm128(
    const float* __restrict__ A, long long sAb,
    const float* __restrict__ B, long long sBb,
    const float* __restrict__ bias, long long sbias, int has_bias,
    float* __restrict__ C, long long sCb, int M)
{
    constexpr int KC = 32;
    constexpr int PITCH = 132;   // 16B-aligned rows (132*4=528)
    __shared__ float As[KC * PITCH];   // As[kk][row] (transposed)
    __shared__ float Bs[KC * PITCH];   // Bs[kk][col]
    const int bz = blockIdx.y;
    A += (long long)bz * sAb;
    B += (long long)bz * sBb;
    C += (long long)bz * sCb;
    if (has_bias) bias += (long long)bz * sbias;

    const int t  = threadIdx.x;
    const int tx = t & 15;      // col group
    const int ty = t >> 4;      // row group
    const int row0 = blockIdx.x * 128;

    float acc[8][8];
#pragma unroll
    for (int i = 0; i < 8; ++i)
#pragma unroll
        for (int j = 0; j < 8; ++j) acc[i][j] = 0.0f;

    for (int kc = 0; kc < 128; kc += KC) {
        __syncthreads();
#pragma unroll
        for (int i = 0; i < 4; ++i) {
            int idx = t + i * 256;          // 1024 float4
            int r   = idx >> 3;             // 8 float4 per row
            int kq  = idx & 7;
            int gr  = row0 + r; gr = (gr < M) ? gr : (M - 1);
            const float4 v = *(const float4*)(A + (long long)gr * HID + kc + kq * 4);
            As[(kq * 4 + 0) * PITCH + r] = v.x;
            As[(kq * 4 + 1) * PITCH + r] = v.y;
            As[(kq * 4 + 2) * PITCH + r] = v.z;
            As[(kq * 4 + 3) * PITCH + r] = v.w;
        }
#pragma unroll
        for (int i = 0; i < 4; ++i) {
            int idx = t + i * 256;
            int k   = idx >> 5;             // 32 float4 per row
            int c4  = idx & 31;
            const float4 v = *(const float4*)(B + (long long)(kc + k) * HID + c4 * 4);
            *(float4*)(&Bs[k * PITCH + c4 * 4]) = v;
        }
        __syncthreads();
#pragma unroll
        for (int kk = 0; kk < KC; ++kk) {
            float a[8], bb[8];
            const float* Ap = &As[kk * PITCH + ty * 8];
            const float* Bp = &Bs[kk * PITCH + tx * 8];
            *(float4*)&a[0]  = *(const float4*)(Ap);
            *(float4*)&a[4]  = *(const float4*)(Ap + 4);
            *(float4*)&bb[0] = *(const float4*)(Bp);
            *(float4*)&bb[4] = *(const float4*)(Bp + 4);
#pragma unroll
            for (int ri = 0; ri < 8; ++ri)
#pragma unroll
                for (int ci = 0; ci < 8; ++ci)
                    acc[ri][ci] += a[ri] * bb[ci];
        }
    }

    float bv[8];
#pragma unroll
    for (int ci = 0; ci < 8; ++ci) bv[ci] = has_bias ? bias[tx * 8 + ci] : 0.0f;

#pragma unroll
    for (int ri = 0; ri < 8; ++ri) {
        int gr = row0 + ty * 8 + ri;
        if (gr < M) {
            float4 o0 = { acc[ri][0] + bv[0], acc[ri][1] + bv[1], acc[ri][2] + bv[2], acc[ri][3] + bv[3] };
            float4 o1 = { acc[ri][4] + bv[4], acc[ri][5] + bv[5], acc[ri][6] + bv[6], acc[ri][7] + bv[7] };
            *(float4*)(C + (long long)gr * HID + tx * 8)     = o0;
            *(float4*)(C + (long long)gr * HID + tx * 8 + 4) = o1;
        }
    }
}

// ---------------- wr_eff[r][f][h] = sum_d Wg[r][f][h*32+d] * attn_r[r][h*32+d] ----------------
__global__ void wreff_kernel(const float* __restrict__ Wg, const float* __restrict__ attn_r,
                             float* __restrict__ wreff)
{
    int tid = blockIdx.x * 256 + threadIdx.x;
    if (tid >= R_REL * 128 * 4) return;
    int r = tid >> 9;
    int f = (tid >> 2) & 127;
    int h = tid & 3;
    float s = 0.0f;
#pragma unroll
    for (int d = 0; d < 32; ++d)
        s += Wg[r * 16384 + f * 128 + h * 32 + d] * attn_r[r * 128 + h * 32 + d];
    wreff[tid] = s;
}

// ---------------- er[r][n][h] = dstT[n,:] @ wr_eff[r][:,h] ; one wave per (r,n) ----------------
__global__ __launch_bounds__(256) void er_kernel(const float* __restrict__ dstT,
                                                 const float* __restrict__ wreff,
                                                 float* __restrict__ er)
{
    int gid = blockIdx.x * 4 + (threadIdx.x >> 6);
    int r = gid / N_NODES, n = gid - r * N_NODES;
    int lane = threadIdx.x & 63;
    float d0 = dstT[(size_t)n * HID + lane];
    float d1 = dstT[(size_t)n * HID + 64 + lane];
    float4 w0 = *(const float4*)(wreff + r * 512 + lane * 4);
    float4 w1 = *(const float4*)(wreff + r * 512 + (64 + lane) * 4);
    float p0 = d0 * w0.x + d1 * w1.x;
    float p1 = d0 * w0.y + d1 * w1.y;
    float p2 = d0 * w0.z + d1 * w1.z;
    float p3 = d0 * w0.w + d1 * w1.w;
#pragma unroll
    for (int off = 32; off >= 1; off >>= 1) {
        p0 += __shfl_down(p0, off);
        p1 += __shfl_down(p1, off);
        p2 += __shfl_down(p2, off);
        p3 += __shfl_down(p3, off);
    }
    if (lane == 0) {
        float4 o = { p0, p1, p2, p3 };
        *(float4*)(er + (size_t)gid * 4) = o;
    }
}

// ---------------- el[r][n][h] = sum_d hs[r][n][h*32+d] * attn_l[r][h*32+d] ----------------
__global__ __launch_bounds__(256) void el_kernel(const float* __restrict__ hs,
                                                 const float* __restrict__ attn_l,
                                                 float* __restrict__ el)
{
    int gid = blockIdx.x * 2 + (threadIdx.x >> 7);
    int r = gid / N_NODES;
    int c = threadIdx.x & 127;
    float v = hs[(size_t)gid * HD + c] * attn_l[r * HD + c];
    v += __shfl_down(v, 16, 32);
    v += __shfl_down(v, 8, 32);
    v += __shfl_down(v, 4, 32);
    v += __shfl_down(v, 2, 32);
    v += __shfl_down(v, 1, 32);
    if ((c & 31) == 0) el[(size_t)gid * 4 + (c >> 5)] = v;
}

// ---------------- CSR build ----------------
__global__ void count_kernel(const int* __restrict__ dst_idx, int* __restrict__ counts)
{
    int tid = blockIdx.x * 256 + threadIdx.x;
    if (tid >= R_REL * E_EDGES) return;
    int r = tid / E_EDGES;
    atomicAdd(&counts[r * N_NODES + dst_idx[tid]], 1);
}

__global__ void blocksum_kernel(const int* __restrict__ counts, int* __restrict__ bsums)
{
    int r = blockIdx.y;
    int i = blockIdx.x * 256 + threadIdx.x;
    int v = (i < N_NODES) ? counts[r * N_NODES + i] : 0;
#pragma unroll
    for (int off = 32; off >= 1; off >>= 1) v += __shfl_down(v, off);
    __shared__ int wsum[4];
    int lane = threadIdx.x & 63, w = threadIdx.x >> 6;
    if (lane == 0) wsum[w] = v;
    __syncthreads();
    if (threadIdx.x == 0) bsums[r * NBLK + blockIdx.x] = wsum[0] + wsum[1] + wsum[2] + wsum[3];
}

__global__ void scan_bsums(const int* __restrict__ bsums, int* __restrict__ boffs,
                           int* __restrict__ offs)
{
    int r = blockIdx.x;
    if (threadIdx.x != 0) return;
    int run = 0;
    for (int b = 0; b < NBLK; ++b) { boffs[r * NBLK + b] = run; run += bsums[r * NBLK + b]; }
    offs[r * (N_NODES + 1) + N_NODES] = run;
}

__global__ void scan_final(const int* __restrict__ counts, const int* __restrict__ boffs,
                           int* __restrict__ offs, int* __restrict__ cursor)
{
    int r = blockIdx.y;
    int i = blockIdx.x * 256 + threadIdx.x;
    int t = threadIdx.x;
    int v = (i < N_NODES) ? counts[r * N_NODES + i] : 0;
    __shared__ int sd[256];
    sd[t] = v;
    __syncthreads();
    for (int off = 1; off < 256; off <<= 1) {
        int y = (t >= off) ? sd[t - off] : 0;
        __syncthreads();
        sd[t] += y;
        __syncthreads();
    }
    int excl = sd[t] - v + boffs[r * NBLK + blockIdx.x];
    if (i < N_NODES) {
        offs[r * (N_NODES + 1) + i] = excl;
        cursor[r * N_NODES + i] = excl;
    }
}

__global__ void scatter_kernel(const int* __restrict__ src_idx, const int* __restrict__ dst_idx,
                               int* __restrict__ cursor, int* __restrict__ csr_src)
{
    int tid = blockIdx.x * 256 + threadIdx.x;
    if (tid >= R_REL * E_EDGES) return;
    int r = tid / E_EDGES;
    int pos = atomicAdd(&cursor[r * N_NODES + dst_idx[tid]], 1);
    csr_src[r * E_EDGES + pos] = src_idx[tid];
}

// ---------------- node-centric GAT aggregation: one wave per (r,n) ----------------
__global__ __launch_bounds__(256) void agg_kernel(
    const float* __restrict__ el, const float* __restrict__ er,
    const float* __restrict__ hs, const int* __restrict__ offs,
    const int* __restrict__ csr_src, const float* __restrict__ bias_g,
    float* __restrict__ zr)
{
    int wid = blockIdx.x * 4 + (threadIdx.x >> 6);
    int r = wid / N_NODES, n = wid - r * N_NODES;
    int lane = threadIdx.x & 63;
    int h0 = lane >> 5;                 // head of col c0 (0/1); head of c1 is h0+2
    int c0 = lane, c1 = lane + 64;

    const float4 er4 = *(const float4*)(er + (size_t)wid * 4);
    float er0 = h0 ? er4.y : er4.x;
    float er1 = h0 ? er4.w : er4.z;

    int beg = offs[r * (N_NODES + 1) + n];
    int end = offs[r * (N_NODES + 1) + n + 1];
    const int*   srcs = csr_src + (size_t)r * E_EDGES;
    const float* elr  = el + (size_t)r * N_NODES * 4;
    const float* hsr  = hs + (size_t)r * N_NODES * HD;

    float m0 = -INFINITY, m1 = -INFINITY;
    for (int j = beg; j < end; ++j) {
        int s = srcs[j];
        float4 el4 = *(const float4*)(elr + (size_t)s * 4);
        float e0 = (h0 ? el4.y : el4.x) + er0;
        float e1 = (h0 ? el4.w : el4.z) + er1;
        e0 = e0 > 0.0f ? e0 : 0.2f * e0;
        e1 = e1 > 0.0f ? e1 : 0.2f * e1;
        m0 = fmaxf(m0, e0); m1 = fmaxf(m1, e1);
    }
    float ss0 = 0.0f, ss1 = 0.0f, acc0 = 0.0f, acc1 = 0.0f;
    for (int j = beg; j < end; ++j) {
        int s = srcs[j];
        float4 el4 = *(const float4*)(elr + (size_t)s * 4);
        float e0 = (h0 ? el4.y : el4.x) + er0;
        float e1 = (h0 ? el4.w : el4.z) + er1;
        e0 = e0 > 0.0f ? e0 : 0.2f * e0;
        e1 = e1 > 0.0f ? e1 : 0.2f * e1;
        float ex0 = __expf(e0 - m0), ex1 = __expf(e1 - m1);
        ss0 += ex0; ss1 += ex1;
        acc0 += ex0 * hsr[(size_t)s * HD + c0];
        acc1 += ex1 * hsr[(size_t)s * HD + c1];
    }
    float r0 = acc0 / (ss0 + 1e-9f) + bias_g[r * HD + c0];
    float r1 = acc1 / (ss1 + 1e-9f) + bias_g[r * HD + c1];
    r0 = r0 > 0.0f ? r0 : (__expf(r0) - 1.0f);   // elu
    r1 = r1 > 0.0f ? r1 : (__expf(r1) - 1.0f);
    zr[(size_t)wid * HD + c0] = r0;
    zr[(size_t)wid * HD + c1] = r1;
}

// ---------------- semantic attention ----------------
__device__ __forceinline__ float fast_tanh(float x)
{
    x = fminf(fmaxf(x, -15.0f), 15.0f);
    float e = __expf(2.0f * x);
    return (e - 1.0f) / (e + 1.0f);
}

// one partial per block per relation — NO global atomics
__global__ __launch_bounds__(256) void wsem_kernel(const float* __restrict__ T,
                                                   const float* __restrict__ W2,
                                                   float* __restrict__ partials)
{
    const int r = blockIdx.y;
    const float* Tr = T + (size_t)r * N_NODES * 128;
    const int wave = threadIdx.x >> 6;
    const int lane = threadIdx.x & 63;
    const int gwave = blockIdx.x * 4 + wave;
    const float w2a = W2[lane], w2b = W2[64 + lane];
    float p = 0.0f;
    for (int n = gwave; n < N_NODES; n += WSEM_BLOCKS * 4) {
        float x0 = Tr[(size_t)n * 128 + lane];
        float x1 = Tr[(size_t)n * 128 + 64 + lane];
        p += fast_tanh(x0) * w2a + fast_tanh(x1) * w2b;
    }
#pragma unroll
    for (int off = 32; off >= 1; off >>= 1) p += __shfl_down(p, off);
    __shared__ float ws[4];
    if (lane == 0) ws[wave] = p;
    __syncthreads();
    if (threadIdx.x == 0)
        partials[r * WSEM_BLOCKS + blockIdx.x] = ws[0] + ws[1] + ws[2] + ws[3];
}

// single block: sum partials per relation, softmax over relations
__global__ __launch_bounds__(256) void softmax_a(const float* __restrict__ partials,
                                                 float* __restrict__ a,
                                                 float* __restrict__ out)
{
    __shared__ float sm[3];
    const int t = threadIdx.x;
    if (t < 192) {
        const int r = t >> 6, lane = t & 63;
        float v = 0.0f;
        for (int i = lane; i < WSEM_BLOCKS; i += 64) v += partials[r * WSEM_BLOCKS + i];
#pragma unroll
        for (int off = 32; off >= 1; off >>= 1) v += __shfl_down(v, off);
        if (lane == 0) sm[r] = v;
    }
    __syncthreads();
    if (t == 0) {
        float w0 = sm[0] / (float)N_NODES;
        float w1 = sm[1] / (float)N_NODES;
        float w2 = sm[2] / (float)N_NODES;
        float m = fmaxf(w0, fmaxf(w1, w2));
        float e0 = __expf(w0 - m), e1 = __expf(w1 - m), e2 = __expf(w2 - m);
        float s = e0 + e1 + e2;
        a[0] = e0 / s; a[1] = e1 / s; a[2] = e2 / s;
        out[(size_t)N_NODES * HD + 0] = a[0];
        out[(size_t)N_NODES * HD + 1] = a[1];
        out[(size_t)N_NODES * HD + 2] = a[2];
    }
}

__global__ __launch_bounds__(256) void combine_kernel(const float* __restrict__ zr,
                                                      const float* __restrict__ a,
                                                      float* __restrict__ out)
{
    size_t i = (size_t)blockIdx.x * 256 + threadIdx.x;   // float4 index, exact grid
    float a0 = a[0], a1 = a[1], a2 = a[2];
    const float4 v0 = ((const float4*)zr)[i];
    const float4 v1 = ((const float4*)(zr + (size_t)N_NODES * HD))[i];
    const float4 v2 = ((const float4*)(zr + 2 * (size_t)N_NODES * HD))[i];
    float4 o = { a0 * v0.x + a1 * v1.x + a2 * v2.x,
                 a0 * v0.y + a1 * v1.y + a2 * v2.y,
                 a0 * v0.z + a1 * v1.z + a2 * v2.z,
                 a0 * v0.w + a1 * v1.w + a2 * v2.w };
    ((float4*)out)[i] = o;
}

// ---------------- launch ----------------
extern "C" void kernel_launch(void* const* d_in, const int* in_sizes, int n_in,
                              void* d_out, int out_size, void* d_ws, size_t ws_size,
                              hipStream_t stream)
{
    const float* dst_feat  = (const float*)d_in[0];
    const float* src_feats = (const float*)d_in[1];
    const int*   src_idx   = (const int*)d_in[2];
    const int*   dst_idx   = (const int*)d_in[3];
    const float* Wt_dst    = (const float*)d_in[4];
    const float* bt_dst    = (const float*)d_in[5];
    const float* Wt_src    = (const float*)d_in[6];
    const float* bt_src    = (const float*)d_in[7];
    const float* Wg        = (const float*)d_in[8];
    const float* attn_l    = (const float*)d_in[9];
    const float* attn_r    = (const float*)d_in[10];
    const float* bias_g    = (const float*)d_in[11];
    const float* W1        = (const float*)d_in[12];
    const float* b1        = (const float*)d_in[13];
    const float* W2        = (const float*)d_in[14];
    float* out = (float*)d_out;

    char* ws = (char*)d_ws;
    float* dstT     = (float*)(ws + OFF_DSTT);
    float* srcT     = (float*)(ws + OFF_B1);    // later reused as z_r
    float* zr       = srcT;
    float* hs       = (float*)(ws + OFF_B2);    // later reused as T
    float* Tbuf     = hs;
    float* el       = (float*)(ws + OFF_EL);
    float* er       = (float*)(ws + OFF_ER);
    float* wreff    = (float*)(ws + OFF_WREFF);
    int*   counts   = (int*)(ws + OFF_CNT);
    int*   offs     = (int*)(ws + OFF_OFFS);
    int*   cursor   = (int*)(ws + OFF_CUR);
    int*   bsums    = (int*)(ws + OFF_BSUM);
    int*   boffs    = (int*)(ws + OFF_BOFF);
    int*   csr      = (int*)(ws + OFF_CSR);
    float* abuf     = (float*)(ws + OFF_ABUF);
    float* partials = (float*)(ws + OFF_PART);

    hipMemsetAsync(counts, 0, (size_t)R_REL * N_NODES * 4, stream);

    // input projections
    gemm128<<<dim3(782, 1), 256, 0, stream>>>(dst_feat, 0, Wt_dst, 0, bt_dst, 0, 1,
                                              dstT, 0, N_NODES);
    gemm128<<<dim3(782, 3), 256, 0, stream>>>(src_feats, (long long)N_NODES * HID,
                                              Wt_src, 128 * 128, bt_src, 128, 1,
                                              srcT, (long long)N_NODES * HID, N_NODES);
    // hs = srcT @ Wg (no bias)
    gemm128<<<dim3(782, 3), 256, 0, stream>>>(srcT, (long long)N_NODES * HID,
                                              Wg, 128 * 128, nullptr, 0, 0,
                                              hs, (long long)N_NODES * HID, N_NODES);
    // attention logits
    wreff_kernel<<<6, 256, 0, stream>>>(Wg, attn_r, wreff);
    er_kernel<<<75000, 256, 0, stream>>>(dstT, wreff, er);
    el_kernel<<<150000, 256, 0, stream>>>(hs, attn_l, el);
    // CSR by dst
    count_kernel<<<3750, 256, 0, stream>>>(dst_idx, counts);
    blocksum_kernel<<<dim3(NBLK, 3), 256, 0, stream>>>(counts, bsums);
    scan_bsums<<<3, 64, 0, stream>>>(bsums, boffs, offs);
    scan_final<<<dim3(NBLK, 3), 256, 0, stream>>>(counts, boffs, offs, cursor);
    scatter_kernel<<<3750, 256, 0, stream>>>(src_idx, dst_idx, cursor, csr);
    // edge-softmax + aggregation (pull), writes z_r into B1 (srcT dead)
    agg_kernel<<<75000, 256, 0, stream>>>(el, er, hs, offs, csr, bias_g, zr);
    // semantic attention: T = Zm @ W1 + b1 into B2 (hs dead)
    gemm128<<<dim3(2344, 1), 256, 0, stream>>>(zr, 0, W1, 0, b1, 0, 1,
                                               Tbuf, 0, R_REL * N_NODES);
    wsem_kernel<<<dim3(WSEM_BLOCKS, 3), 256, 0, stream>>>(Tbuf, W2, partials);
    softmax_a<<<1, 256, 0, stream>>>(partials, abuf, out);
    combine_kernel<<<12500, 256, 0, stream>>>(zr, abuf, out);
}

// Round 3
// 1101.003 us; speedup vs baseline: 4.6218x; 1.1649x over previous
//
#include <hip/hip_runtime.h>
#include <hip/hip_bf16.h>
#include <math.h>

#define N_NODES 100000
#define R_REL 3
#define E_EDGES 320000
#define HID 128
#define HD 128
#define NBLK 391   // ceil(N/256)
#define WSEM_BLOCKS 200

// ---------------- workspace layout (byte offsets, all 256B aligned) ----------------
static constexpr size_t OFF_DSTT  = 0;                     // dstT N*128 f32; later reused as ex_csr (R*E*4 f32 = 15.36MB < 51.2MB)
static constexpr size_t OFF_B1    = 51200000;              // srcT / z_r: R*N*128 f32
static constexpr size_t OFF_B2    = 204800000;             // hs / T: R*N*128 f32
static constexpr size_t OFF_EL    = 358400000;             // R*N*4 f32
static constexpr size_t OFF_ER    = 363200000;             // R*N*4 f32
static constexpr size_t OFF_WREFF = 368000000;             // R*128*4 f32
static constexpr size_t OFF_CNT   = 368006144;             // R*N i32
static constexpr size_t OFF_OFFS  = 369206144;             // R*(N+1) i32
static constexpr size_t OFF_CUR   = 370406272;             // R*N i32
static constexpr size_t OFF_BSUM  = 371606272;             // R*NBLK i32
static constexpr size_t OFF_BOFF  = 371611136;             // R*NBLK i32
static constexpr size_t OFF_CSR   = 371616000;             // R*E i32
static constexpr size_t OFF_ABUF  = 375456000;             // 3 f32
static constexpr size_t OFF_PART  = 375456256;             // R*WSEM_BLOCKS f32

typedef __attribute__((ext_vector_type(8))) short short8;
typedef __attribute__((ext_vector_type(4))) float floatx4;

__device__ __forceinline__ unsigned short f2bf(float f)
{
    unsigned u = __float_as_uint(f);
    unsigned r = (u + 0x7FFFu + ((u >> 16) & 1u)) >> 16;   // RNE
    return (unsigned short)r;
}

// ---------------- bf16-MFMA GEMM: C[M,128] = A[M,128] @ B[128,128] (+bias), fp32 in/out --------
// 128x128 block tile, 4 waves, each wave 64x64 (4x4 of 16x16x32 mfma). K staged in 32-chunks.
#define GPITCH 40   // ushorts per LDS row (80B = 5*16B: keeps short8 loads 16B-aligned, breaks pow2 banks)
__global__ __launch_bounds__(256) void gemm_mfma(
    const float* __restrict__ A, long long sAb,
    const float* __restrict__ B, long long sBb,
    const float* __restrict__ bias, long long sbias, int has_bias,
    float* __restrict__ C, long long sCb, int M)
{
    __shared__ unsigned short As[128 * GPITCH];   // As[m][k] bf16
    __shared__ unsigned short Bs[128 * GPITCH];   // Bs[n][k] bf16 (B transposed)
    const int bz = blockIdx.y;
    A += (long long)bz * sAb;
    B += (long long)bz * sBb;
    C += (long long)bz * sCb;
    if (has_bias) bias += (long long)bz * sbias;

    const int t    = threadIdx.x;
    const int wave = t >> 6;
    const int lane = t & 63;
    const int wm   = wave >> 1;      // wave row (0/1)
    const int wn   = wave & 1;       // wave col (0/1)
    const int lm   = lane & 15;
    const int quad = lane >> 4;
    const int row0 = blockIdx.x * 128;

    floatx4 acc[4][4];
#pragma unroll
    for (int i = 0; i < 4; ++i)
#pragma unroll
        for (int j = 0; j < 4; ++j) acc[i][j] = (floatx4){0.f, 0.f, 0.f, 0.f};

    for (int kc = 0; kc < 128; kc += 32) {
        __syncthreads();
        // stage A chunk: 128 rows x 32 k  (1024 float4 items)
#pragma unroll
        for (int i = 0; i < 4; ++i) {
            int item = t + i * 256;
            int r  = item >> 3;
            int kq = item & 7;
            int gr = row0 + r; gr = (gr < M) ? gr : (M - 1);
            const float4 v = *(const float4*)(A + (size_t)gr * 128 + kc + kq * 4);
            uint2 u;
            u.x = (unsigned)f2bf(v.x) | ((unsigned)f2bf(v.y) << 16);
            u.y = (unsigned)f2bf(v.z) | ((unsigned)f2bf(v.w) << 16);
            *(uint2*)(&As[r * GPITCH + kq * 4]) = u;   // byte addr r*80+kq*8, 8B aligned
        }
        // stage B chunk transposed: 32 k x 128 n -> Bs[n][k]  (512 items: k-pair x n4)
#pragma unroll
        for (int i = 0; i < 2; ++i) {
            int item = t + i * 256;
            int kp = item >> 5;            // 0..15 (k pair)
            int n4 = (item & 31) * 4;
            int k  = kc + kp * 2;
            const float4 b0 = *(const float4*)(B + (size_t)k * 128 + n4);
            const float4 b1 = *(const float4*)(B + (size_t)(k + 1) * 128 + n4);
            *(unsigned*)(&Bs[(n4 + 0) * GPITCH + kp * 2]) = (unsigned)f2bf(b0.x) | ((unsigned)f2bf(b1.x) << 16);
            *(unsigned*)(&Bs[(n4 + 1) * GPITCH + kp * 2]) = (unsigned)f2bf(b0.y) | ((unsigned)f2bf(b1.y) << 16);
            *(unsigned*)(&Bs[(n4 + 2) * GPITCH + kp * 2]) = (unsigned)f2bf(b0.z) | ((unsigned)f2bf(b1.z) << 16);
            *(unsigned*)(&Bs[(n4 + 3) * GPITCH + kp * 2]) = (unsigned)f2bf(b0.w) | ((unsigned)f2bf(b1.w) << 16);
        }
        __syncthreads();

        short8 af[4], bf[4];
#pragma unroll
        for (int mt = 0; mt < 4; ++mt)
            af[mt] = *(const short8*)(&As[(wm * 64 + mt * 16 + lm) * GPITCH + quad * 8]);
#pragma unroll
        for (int nt = 0; nt < 4; ++nt)
            bf[nt] = *(const short8*)(&Bs[(wn * 64 + nt * 16 + lm) * GPITCH + quad * 8]);
#pragma unroll
        for (int mt = 0; mt < 4; ++mt)
#pragma unroll
            for (int nt = 0; nt < 4; ++nt)
                acc[mt][nt] = __builtin_amdgcn_mfma_f32_16x16x32_bf16(af[mt], bf[nt], acc[mt][nt], 0, 0, 0);
    }

    // epilogue: D row = quad*4 + reg, col = lm (within 16x16 tile)
#pragma unroll
    for (int nt = 0; nt < 4; ++nt) {
        const int col = wn * 64 + nt * 16 + lm;
        const float bv = has_bias ? bias[col] : 0.0f;
#pragma unroll
        for (int mt = 0; mt < 4; ++mt) {
            const int rowb = row0 + wm * 64 + mt * 16 + quad * 4;
#pragma unroll
            for (int rg = 0; rg < 4; ++rg) {
                int gr = rowb + rg;
                if (gr < M) C[(size_t)gr * 128 + col] = acc[mt][nt][rg] + bv;
            }
        }
    }
}

// ---------------- wr_eff[r][f][h] = sum_d Wg[r][f][h*32+d] * attn_r[r][h*32+d] ----------------
__global__ void wreff_kernel(const float* __restrict__ Wg, const float* __restrict__ attn_r,
                             float* __restrict__ wreff)
{
    int tid = blockIdx.x * 256 + threadIdx.x;
    if (tid >= R_REL * 128 * 4) return;
    int r = tid >> 9;
    int f = (tid >> 2) & 127;
    int h = tid & 3;
    float s = 0.0f;
#pragma unroll
    for (int d = 0; d < 32; ++d)
        s += Wg[r * 16384 + f * 128 + h * 32 + d] * attn_r[r * 128 + h * 32 + d];
    wreff[tid] = s;
}

// ---------------- er[r][n][h] = dstT[n,:] @ wr_eff[r][:,h] ; one wave per (r,n) ----------------
__global__ __launch_bounds__(256) void er_kernel(const float* __restrict__ dstT,
                                                 const float* __restrict__ wreff,
                                                 float* __restrict__ er)
{
    int gid = blockIdx.x * 4 + (threadIdx.x >> 6);
    int r = gid / N_NODES, n = gid - r * N_NODES;
    int lane = threadIdx.x & 63;
    float d0 = dstT[(size_t)n * HID + lane];
    float d1 = dstT[(size_t)n * HID + 64 + lane];
    float4 w0 = *(const float4*)(wreff + r * 512 + lane * 4);
    float4 w1 = *(const float4*)(wreff + r * 512 + (64 + lane) * 4);
    float p0 = d0 * w0.x + d1 * w1.x;
    float p1 = d0 * w0.y + d1 * w1.y;
    float p2 = d0 * w0.z + d1 * w1.z;
    float p3 = d0 * w0.w + d1 * w1.w;
#pragma unroll
    for (int off = 32; off >= 1; off >>= 1) {
        p0 += __shfl_down(p0, off);
        p1 += __shfl_down(p1, off);
        p2 += __shfl_down(p2, off);
        p3 += __shfl_down(p3, off);
    }
    if (lane == 0) {
        float4 o = { p0, p1, p2, p3 };
        *(float4*)(er + (size_t)gid * 4) = o;
    }
}

// ---------------- el[r][n][h] = sum_d hs[r][n][h*32+d] * attn_l[r][h*32+d] ----------------
__global__ __launch_bounds__(256) void el_kernel(const float* __restrict__ hs,
                                                 const float* __restrict__ attn_l,
                                                 float* __restrict__ el)
{
    int gid = blockIdx.x * 2 + (threadIdx.x >> 7);
    int r = gid / N_NODES;
    int c = threadIdx.x & 127;
    float v = hs[(size_t)gid * HD + c] * attn_l[r * HD + c];
    v += __shfl_down(v, 16, 32);
    v += __shfl_down(v, 8, 32);
    v += __shfl_down(v, 4, 32);
    v += __shfl_down(v, 2, 32);
    v += __shfl_down(v, 1, 32);
    if ((c & 31) == 0) el[(size_t)gid * 4 + (c >> 5)] = v;
}

// ---------------- CSR build ----------------
__global__ void count_kernel(const int* __restrict__ dst_idx, int* __restrict__ counts)
{
    int tid = blockIdx.x * 256 + threadIdx.x;
    if (tid >= R_REL * E_EDGES) return;
    int r = tid / E_EDGES;
    atomicAdd(&counts[r * N_NODES + dst_idx[tid]], 1);
}

__global__ void blocksum_kernel(const int* __restrict__ counts, int* __restrict__ bsums)
{
    int r = blockIdx.y;
    int i = blockIdx.x * 256 + threadIdx.x;
    int v = (i < N_NODES) ? counts[r * N_NODES + i] : 0;
#pragma unroll
    for (int off = 32; off >= 1; off >>= 1) v += __shfl_down(v, off);
    __shared__ int wsum[4];
    int lane = threadIdx.x & 63, w = threadIdx.x >> 6;
    if (lane == 0) wsum[w] = v;
    __syncthreads();
    if (threadIdx.x == 0) bsums[r * NBLK + blockIdx.x] = wsum[0] + wsum[1] + wsum[2] + wsum[3];
}

__global__ void scan_bsums(const int* __restrict__ bsums, int* __restrict__ boffs,
                           int* __restrict__ offs)
{
    int r = blockIdx.x;
    if (threadIdx.x != 0) return;
    int run = 0;
    for (int b = 0; b < NBLK; ++b) { boffs[r * NBLK + b] = run; run += bsums[r * NBLK + b]; }
    offs[r * (N_NODES + 1) + N_NODES] = run;
}

__global__ void scan_final(const int* __restrict__ counts, const int* __restrict__ boffs,
                           int* __restrict__ offs, int* __restrict__ cursor)
{
    int r = blockIdx.y;
    int i = blockIdx.x * 256 + threadIdx.x;
    int t = threadIdx.x;
    int v = (i < N_NODES) ? counts[r * N_NODES + i] : 0;
    __shared__ int sd[256];
    sd[t] = v;
    __syncthreads();
    for (int off = 1; off < 256; off <<= 1) {
        int y = (t >= off) ? sd[t - off] : 0;
        __syncthreads();
        sd[t] += y;
        __syncthreads();
    }
    int excl = sd[t] - v + boffs[r * NBLK + blockIdx.x];
    if (i < N_NODES) {
        offs[r * (N_NODES + 1) + i] = excl;
        cursor[r * N_NODES + i] = excl;
    }
}

// scatter + fused edge logits: ex = exp(leaky(el[s]+er[d])) stored in CSR slot (no max-
// subtraction: logits are O(1), and softmax is shift-invariant so result is identical)
__global__ void scatter_ex(const int* __restrict__ src_idx, const int* __restrict__ dst_idx,
                           const float* __restrict__ el, const float* __restrict__ er,
                           int* __restrict__ cursor, int* __restrict__ csr_src,
                           float* __restrict__ ex_csr)
{
    int tid = blockIdx.x * 256 + threadIdx.x;
    if (tid >= R_REL * E_EDGES) return;
    int r = tid / E_EDGES;
    int s = src_idx[tid], d = dst_idx[tid];
    float4 a = *(const float4*)(el + ((size_t)r * N_NODES + s) * 4);
    float4 b = *(const float4*)(er + ((size_t)r * N_NODES + d) * 4);
    float e0 = a.x + b.x, e1 = a.y + b.y, e2 = a.z + b.z, e3 = a.w + b.w;
    e0 = e0 > 0.f ? e0 : 0.2f * e0;
    e1 = e1 > 0.f ? e1 : 0.2f * e1;
    e2 = e2 > 0.f ? e2 : 0.2f * e2;
    e3 = e3 > 0.f ? e3 : 0.2f * e3;
    float4 ex = { __expf(e0), __expf(e1), __expf(e2), __expf(e3) };
    int pos = atomicAdd(&cursor[r * N_NODES + d], 1);
    csr_src[(size_t)r * E_EDGES + pos] = s;
    *(float4*)(ex_csr + ((size_t)r * E_EDGES + pos) * 4) = ex;
}

// ---------------- node-centric aggregation: one wave per (r,n), ILP-unrolled gathers ----------
__global__ __launch_bounds__(256) void agg_kernel(
    const float* __restrict__ ex_csr, const float* __restrict__ hs,
    const int* __restrict__ offs, const int* __restrict__ csr_src,
    const float* __restrict__ bias_g, float* __restrict__ zr)
{
    int wid = blockIdx.x * 4 + (threadIdx.x >> 6);
    int r = wid / N_NODES, n = wid - r * N_NODES;
    int lane = threadIdx.x & 63;
    int h0 = lane >> 5;             // head of col c0 (0/1); col c1 is head h0+2
    int c0 = lane, c1 = lane + 64;

    int beg = offs[r * (N_NODES + 1) + n];
    int end = offs[r * (N_NODES + 1) + n + 1];
    const int*   srcs = csr_src + (size_t)r * E_EDGES;
    const float* exc  = ex_csr + (size_t)r * E_EDGES * 4;
    const float* hsr  = hs + (size_t)r * N_NODES * HD;

    float ss0 = 0.f, ss1 = 0.f, acc0 = 0.f, acc1 = 0.f;
    for (int base = beg; base < end; base += 64) {
        int j = base + lane;
        bool v = j < end;
        int jj = v ? j : base;                       // base < end guaranteed here
        int sv = srcs[jj];
        float4 exv = *(const float4*)(exc + (size_t)jj * 4);
        if (!v) { exv.x = 0.f; exv.y = 0.f; exv.z = 0.f; exv.w = 0.f; }
        int cnt4 = (min(64, end - base) + 3) & ~3;   // pad to 4: padded lanes have ex==0
        for (int k = 0; k < cnt4; k += 4) {
            int s0 = __shfl(sv, k),     s1 = __shfl(sv, k + 1);
            int s2 = __shfl(sv, k + 2), s3 = __shfl(sv, k + 3);
            float x0 = __shfl(exv.x, k), y0 = __shfl(exv.y, k), z0 = __shfl(exv.z, k), w0 = __shfl(exv.w, k);
            float x1 = __shfl(exv.x, k+1), y1 = __shfl(exv.y, k+1), z1 = __shfl(exv.z, k+1), w1 = __shfl(exv.w, k+1);
            float x2 = __shfl(exv.x, k+2), y2 = __shfl(exv.y, k+2), z2 = __shfl(exv.z, k+2), w2 = __shfl(exv.w, k+2);
            float x3 = __shfl(exv.x, k+3), y3 = __shfl(exv.y, k+3), z3 = __shfl(exv.z, k+3), w3 = __shfl(exv.w, k+3);
            // independent gathers: 8 loads in flight
            float g00 = hsr[(size_t)s0 * HD + c0], g01 = hsr[(size_t)s0 * HD + c1];
            float g10 = hsr[(size_t)s1 * HD + c0], g11 = hsr[(size_t)s1 * HD + c1];
            float g20 = hsr[(size_t)s2 * HD + c0], g21 = hsr[(size_t)s2 * HD + c1];
            float g30 = hsr[(size_t)s3 * HD + c0], g31 = hsr[(size_t)s3 * HD + c1];
            float e00 = h0 ? y0 : x0, e10 = h0 ? w0 : z0;
            float e01 = h0 ? y1 : x1, e11 = h0 ? w1 : z1;
            float e02 = h0 ? y2 : x2, e12 = h0 ? w2 : z2;
            float e03 = h0 ? y3 : x3, e13 = h0 ? w3 : z3;
            ss0 += e00 + e01 + e02 + e03;
            ss1 += e10 + e11 + e12 + e13;
            acc0 += e00 * g00 + e01 * g10 + e02 * g20 + e03 * g30;
            acc1 += e10 * g01 + e11 * g11 + e12 * g21 + e13 * g31;
        }
    }
    float r0 = acc0 / (ss0 + 1e-9f) + bias_g[r * HD + c0];
    float r1 = acc1 / (ss1 + 1e-9f) + bias_g[r * HD + c1];
    r0 = r0 > 0.0f ? r0 : (__expf(r0) - 1.0f);   // elu
    r1 = r1 > 0.0f ? r1 : (__expf(r1) - 1.0f);
    zr[(size_t)wid * HD + c0] = r0;
    zr[(size_t)wid * HD + c1] = r1;
}

// ---------------- semantic attention ----------------
__device__ __forceinline__ float fast_tanh(float x)
{
    x = fminf(fmaxf(x, -15.0f), 15.0f);
    float e = __expf(2.0f * x);
    return (e - 1.0f) / (e + 1.0f);
}

__global__ __launch_bounds__(256) void wsem_kernel(const float* __restrict__ T,
                                                   const float* __restrict__ W2,
                                                   float* __restrict__ partials)
{
    const int r = blockIdx.y;
    const float* Tr = T + (size_t)r * N_NODES * 128;
    const int wave = threadIdx.x >> 6;
    const int lane = threadIdx.x & 63;
    const int gwave = blockIdx.x * 4 + wave;
    const float w2a = W2[lane], w2b = W2[64 + lane];
    float p = 0.0f;
    for (int n = gwave; n < N_NODES; n += WSEM_BLOCKS * 4) {
        float x0 = Tr[(size_t)n * 128 + lane];
        float x1 = Tr[(size_t)n * 128 + 64 + lane];
        p += fast_tanh(x0) * w2a + fast_tanh(x1) * w2b;
    }
#pragma unroll
    for (int off = 32; off >= 1; off >>= 1) p += __shfl_down(p, off);
    __shared__ float ws[4];
    if (lane == 0) ws[wave] = p;
    __syncthreads();
    if (threadIdx.x == 0)
        partials[r * WSEM_BLOCKS + blockIdx.x] = ws[0] + ws[1] + ws[2] + ws[3];
}

__global__ __launch_bounds__(256) void softmax_a(const float* __restrict__ partials,
                                                 float* __restrict__ a,
                                                 float* __restrict__ out)
{
    __shared__ float sm[3];
    const int t = threadIdx.x;
    if (t < 192) {
        const int r = t >> 6, lane = t & 63;
        float v = 0.0f;
        for (int i = lane; i < WSEM_BLOCKS; i += 64) v += partials[r * WSEM_BLOCKS + i];
#pragma unroll
        for (int off = 32; off >= 1; off >>= 1) v += __shfl_down(v, off);
        if (lane == 0) sm[r] = v;
    }
    __syncthreads();
    if (t == 0) {
        float w0 = sm[0] / (float)N_NODES;
        float w1 = sm[1] / (float)N_NODES;
        float w2 = sm[2] / (float)N_NODES;
        float m = fmaxf(w0, fmaxf(w1, w2));
        float e0 = __expf(w0 - m), e1 = __expf(w1 - m), e2 = __expf(w2 - m);
        float s = e0 + e1 + e2;
        a[0] = e0 / s; a[1] = e1 / s; a[2] = e2 / s;
        out[(size_t)N_NODES * HD + 0] = a[0];
        out[(size_t)N_NODES * HD + 1] = a[1];
        out[(size_t)N_NODES * HD + 2] = a[2];
    }
}

__global__ __launch_bounds__(256) void combine_kernel(const float* __restrict__ zr,
                                                      const float* __restrict__ a,
                                                      float* __restrict__ out)
{
    size_t i = (size_t)blockIdx.x * 256 + threadIdx.x;   // float4 index, exact grid
    float a0 = a[0], a1 = a[1], a2 = a[2];
    const float4 v0 = ((const float4*)zr)[i];
    const float4 v1 = ((const float4*)(zr + (size_t)N_NODES * HD))[i];
    const float4 v2 = ((const float4*)(zr + 2 * (size_t)N_NODES * HD))[i];
    float4 o = { a0 * v0.x + a1 * v1.x + a2 * v2.x,
                 a0 * v0.y + a1 * v1.y + a2 * v2.y,
                 a0 * v0.z + a1 * v1.z + a2 * v2.z,
                 a0 * v0.w + a1 * v1.w + a2 * v2.w };
    ((float4*)out)[i] = o;
}

// ---------------- launch ----------------
extern "C" void kernel_launch(void* const* d_in, const int* in_sizes, int n_in,
                              void* d_out, int out_size, void* d_ws, size_t ws_size,
                              hipStream_t stream)
{
    const float* dst_feat  = (const float*)d_in[0];
    const float* src_feats = (const float*)d_in[1];
    const int*   src_idx   = (const int*)d_in[2];
    const int*   dst_idx   = (const int*)d_in[3];
    const float* Wt_dst    = (const float*)d_in[4];
    const float* bt_dst    = (const float*)d_in[5];
    const float* Wt_src    = (const float*)d_in[6];
    const float* bt_src    = (const float*)d_in[7];
    const float* Wg        = (const float*)d_in[8];
    const float* attn_l    = (const float*)d_in[9];
    const float* attn_r    = (const float*)d_in[10];
    const float* bias_g    = (const float*)d_in[11];
    const float* W1        = (const float*)d_in[12];
    const float* b1        = (const float*)d_in[13];
    const float* W2        = (const float*)d_in[14];
    float* out = (float*)d_out;

    char* ws = (char*)d_ws;
    float* dstT     = (float*)(ws + OFF_DSTT);
    float* ex_csr   = (float*)(ws + OFF_DSTT);  // aliases dstT: dstT dead after er_kernel
    float* srcT     = (float*)(ws + OFF_B1);    // later reused as z_r
    float* zr       = srcT;
    float* hs       = (float*)(ws + OFF_B2);    // later reused as T
    float* Tbuf     = hs;
    float* el       = (float*)(ws + OFF_EL);
    float* er       = (float*)(ws + OFF_ER);
    float* wreff    = (float*)(ws + OFF_WREFF);
    int*   counts   = (int*)(ws + OFF_CNT);
    int*   offs     = (int*)(ws + OFF_OFFS);
    int*   cursor   = (int*)(ws + OFF_CUR);
    int*   bsums    = (int*)(ws + OFF_BSUM);
    int*   boffs    = (int*)(ws + OFF_BOFF);
    int*   csr      = (int*)(ws + OFF_CSR);
    float* abuf     = (float*)(ws + OFF_ABUF);
    float* partials = (float*)(ws + OFF_PART);

    hipMemsetAsync(counts, 0, (size_t)R_REL * N_NODES * 4, stream);

    // input projections (bf16 MFMA, fp32 I/O)
    gemm_mfma<<<dim3(782, 1), 256, 0, stream>>>(dst_feat, 0, Wt_dst, 0, bt_dst, 0, 1,
                                                dstT, 0, N_NODES);
    gemm_mfma<<<dim3(782, 3), 256, 0, stream>>>(src_feats, (long long)N_NODES * HID,
                                                Wt_src, 128 * 128, bt_src, 128, 1,
                                                srcT, (long long)N_NODES * HID, N_NODES);
    gemm_mfma<<<dim3(782, 3), 256, 0, stream>>>(srcT, (long long)N_NODES * HID,
                                                Wg, 128 * 128, nullptr, 0, 0,
                                                hs, (long long)N_NODES * HID, N_NODES);
    // attention logits
    wreff_kernel<<<6, 256, 0, stream>>>(Wg, attn_r, wreff);
    er_kernel<<<75000, 256, 0, stream>>>(dstT, wreff, er);      // last use of dstT
    el_kernel<<<150000, 256, 0, stream>>>(hs, attn_l, el);
    // CSR by dst
    count_kernel<<<3750, 256, 0, stream>>>(dst_idx, counts);
    blocksum_kernel<<<dim3(NBLK, 3), 256, 0, stream>>>(counts, bsums);
    scan_bsums<<<3, 64, 0, stream>>>(bsums, boffs, offs);
    scan_final<<<dim3(NBLK, 3), 256, 0, stream>>>(counts, boffs, offs, cursor);
    // scatter with fused edge logits -> ex_csr (overwrites dstT region)
    scatter_ex<<<3750, 256, 0, stream>>>(src_idx, dst_idx, el, er, cursor, csr, ex_csr);
    // pull aggregation, writes z_r into B1 (srcT dead)
    agg_kernel<<<75000, 256, 0, stream>>>(ex_csr, hs, offs, csr, bias_g, zr);
    // semantic attention: T = Zm @ W1 + b1 into B2 (hs dead)
    gemm_mfma<<<dim3(2344, 1), 256, 0, stream>>>(zr, 0, W1, 0, b1, 0, 1,
                                                 Tbuf, 0, R_REL * N_NODES);
    wsem_kernel<<<dim3(WSEM_BLOCKS, 3), 256, 0, stream>>>(Tbuf, W2, partials);
    softmax_a<<<1, 256, 0, stream>>>(partials, abuf, out);
    combine_kernel<<<12500, 256, 0, stream>>>(zr, abuf, out);
}

// Round 4
// 781.077 us; speedup vs baseline: 6.5149x; 1.4096x over previous
//
#include <hip/hip_runtime.h>
#include <hip/hip_bf16.h>
#include <math.h>

#define N_NODES 100000
#define R_REL 3
#define E_EDGES 320000
#define HID 128
#define HD 128
#define NBLK 391        // ceil(N/256)
#define GBLK 782        // ceil(N/128)

// ---------------- workspace layout (byte offsets) ----------------
// Region 0 (51.2 MB): ex_csr (15.36 MB) + small prep buffers
static constexpr size_t OFF_EXCSR = 0;                     // R*E*4 f32 = 15,360,000
static constexpr size_t OFF_WTS_T = 16000000;              // R*128*128 bf16 = 98,304
static constexpr size_t OFF_WG_T  = 16098304;              // R*128*128 bf16 = 98,304
static constexpr size_t OFF_W1_T  = 16196608;              // 128*128 bf16 = 32,768
static constexpr size_t OFF_MER   = 16229376;              // R*128*4 f32 = 6,144
static constexpr size_t OFF_CER   = 16235520;              // R*4 f32 = 48 -> 64
static constexpr size_t OFF_PART  = 16235584;              // R*GBLK f32 = 9,384
static constexpr size_t OFF_B1    = 51200000;              // z_r: R*N*128 f32
static constexpr size_t OFF_B2    = 204800000;             // hs: R*N*128 f32
static constexpr size_t OFF_EL    = 358400000;             // R*N*4 f32
static constexpr size_t OFF_ER    = 363200000;             // R*N*4 f32
static constexpr size_t OFF_CNT   = 368006144;             // R*N i32
static constexpr size_t OFF_OFFS  = 369206144;             // R*(N+1) i32
static constexpr size_t OFF_CUR   = 370406272;             // R*N i32
static constexpr size_t OFF_BSUM  = 371606272;             // R*NBLK i32
static constexpr size_t OFF_BOFF  = 371611136;             // R*NBLK i32
static constexpr size_t OFF_CSR   = 371616000;             // R*E i32
static constexpr size_t OFF_ABUF  = 375456000;             // 3 f32

typedef __attribute__((ext_vector_type(8))) short short8;
typedef __attribute__((ext_vector_type(4))) float floatx4;

__device__ __forceinline__ unsigned f2bf(float f)
{
    unsigned u = __float_as_uint(f);
    return (u + 0x7FFFu + ((u >> 16) & 1u)) >> 16;   // RNE
}

__device__ __forceinline__ float fast_tanh(float x)
{
    x = fminf(fmaxf(x, -15.0f), 15.0f);
    float e = __expf(2.0f * x);
    return (e - 1.0f) / (e + 1.0f);
}

// ---------------- weight pre-transpose: dst[n][k] = bf16(src[k][n]) ----------------
__global__ void transpose_bf16(const float* __restrict__ src, unsigned short* __restrict__ dst)
{
    int mat = blockIdx.y;
    int idx = blockIdx.x * 256 + threadIdx.x;   // 64 blocks x 256 = 16384
    int n = idx >> 7, k = idx & 127;
    dst[(size_t)mat * 16384 + n * 128 + k] =
        (unsigned short)f2bf(src[(size_t)mat * 16384 + k * 128 + n]);
}

// ---------------- er prep: wr_eff = reduce(Wg,attn_r); M = Wt_dst@wr_eff; c = bt_dst@wr_eff ----
__global__ __launch_bounds__(512) void prep_er(const float* __restrict__ Wg,
                                               const float* __restrict__ attn_r,
                                               const float* __restrict__ Wt_dst,
                                               const float* __restrict__ bt_dst,
                                               float* __restrict__ M, float* __restrict__ cvec)
{
    const int r = blockIdx.x;
    const int t = threadIdx.x;          // 512 = 128 f x 4 h
    const int f = t >> 2, h = t & 3;
    __shared__ float wr[128][4];
    float s = 0.0f;
#pragma unroll
    for (int d = 0; d < 32; ++d)
        s += Wg[(size_t)r * 16384 + f * 128 + h * 32 + d] * attn_r[r * 128 + h * 32 + d];
    wr[f][h] = s;
    __syncthreads();
    float m = 0.0f;
    for (int k = 0; k < 128; ++k) m += Wt_dst[f * 128 + k] * wr[k][h];
    M[((size_t)r * 128 + f) * 4 + h] = m;
    if (f == 0) {
        float c = 0.0f;
        for (int k = 0; k < 128; ++k) c += bt_dst[k] * wr[k][h];
        cvec[r * 4 + h] = c;
    }
}

// ---------------- er_direct: er[r][n][h] = dst_feat[n,:]·M[r][:,h] + c[r][h] ----------------
__global__ __launch_bounds__(256) void er_direct(const float* __restrict__ dst_feat,
                                                 const float* __restrict__ M,
                                                 const float* __restrict__ cvec,
                                                 float* __restrict__ er)
{
    int n = blockIdx.x * 4 + (threadIdx.x >> 6);
    int lane = threadIdx.x & 63;
    float d0 = dst_feat[(size_t)n * 128 + lane];
    float d1 = dst_feat[(size_t)n * 128 + 64 + lane];
#pragma unroll
    for (int r = 0; r < R_REL; ++r) {
        float4 w0 = *(const float4*)(M + ((size_t)r * 128 + lane) * 4);
        float4 w1 = *(const float4*)(M + ((size_t)r * 128 + 64 + lane) * 4);
        float p0 = d0 * w0.x + d1 * w1.x;
        float p1 = d0 * w0.y + d1 * w1.y;
        float p2 = d0 * w0.z + d1 * w1.z;
        float p3 = d0 * w0.w + d1 * w1.w;
#pragma unroll
        for (int off = 32; off >= 1; off >>= 1) {
            p0 += __shfl_down(p0, off);
            p1 += __shfl_down(p1, off);
            p2 += __shfl_down(p2, off);
            p3 += __shfl_down(p3, off);
        }
        if (lane == 0) {
            float4 c4 = *(const float4*)(cvec + r * 4);
            float4 o = { p0 + c4.x, p1 + c4.y, p2 + c4.z, p3 + c4.w };
            *(float4*)(er + ((size_t)r * N_NODES + n) * 4) = o;
        }
    }
}

// ---------------- fused src pipeline: srcT=src@Wt+bt (LDS only) -> hs=srcT@Wg -> el ----------
// 128-row tile per block, 4 waves each 64x64 (4x4 mfma 16x16x32). B-frags direct from L2.
#define XPITCH 136   // ushorts/row = 272B: 16B-aligned, dword stride 68 == 4 (mod 32) (conflict-free class)
__global__ __launch_bounds__(256) void fused_src_kernel(
    const float* __restrict__ src_feats, const unsigned short* __restrict__ WtsT,
    const float* __restrict__ bt_src, const unsigned short* __restrict__ WgT,
    const float* __restrict__ attn_l, float* __restrict__ hs, float* __restrict__ el)
{
    __shared__ unsigned short Xs[128 * XPITCH];   // 34 KB: input tile, then srcT tile
    __shared__ float els[128][4];
    const int r = blockIdx.y;
    const int row0 = blockIdx.x * 128;
    const int t = threadIdx.x, wave = t >> 6, lane = t & 63;
    const int wm = wave >> 1, wn = wave & 1, lm = lane & 15, quad = lane >> 4;
    const float* A = src_feats + (size_t)r * N_NODES * 128;

    // stage input tile fp32->bf16 (uniform-bank writes)
#pragma unroll
    for (int i = 0; i < 16; ++i) {
        int item = t + i * 256;                 // 4096 = 128 rows x 32 float4
        int m = item >> 5, kq = item & 31;
        int gr = row0 + m; gr = gr < N_NODES ? gr : N_NODES - 1;
        float4 v = *(const float4*)(A + (size_t)gr * 128 + kq * 4);
        uint2 u;
        u.x = f2bf(v.x) | (f2bf(v.y) << 16);
        u.y = f2bf(v.z) | (f2bf(v.w) << 16);
        *(uint2*)(&Xs[m * XPITCH + kq * 4]) = u;
    }
    // preload B1 fragments (Wt_src^T bf16 [n][k]) straight from global/L2
    const unsigned short* B1 = WtsT + r * 16384;
    short8 bfrag[4][4];
#pragma unroll
    for (int nt = 0; nt < 4; ++nt)
#pragma unroll
        for (int kc = 0; kc < 4; ++kc)
            bfrag[nt][kc] = *(const short8*)(B1 + (wn * 64 + nt * 16 + lm) * 128 + kc * 32 + quad * 8);
    __syncthreads();

    floatx4 acc[4][4];
#pragma unroll
    for (int i = 0; i < 4; ++i)
#pragma unroll
        for (int j = 0; j < 4; ++j) acc[i][j] = (floatx4){0.f, 0.f, 0.f, 0.f};

    // GEMM1: srcT tile
#pragma unroll
    for (int kc = 0; kc < 4; ++kc) {
        short8 af[4];
#pragma unroll
        for (int mt = 0; mt < 4; ++mt)
            af[mt] = *(const short8*)(&Xs[(wm * 64 + mt * 16 + lm) * XPITCH + kc * 32 + quad * 8]);
#pragma unroll
        for (int mt = 0; mt < 4; ++mt)
#pragma unroll
            for (int nt = 0; nt < 4; ++nt)
                acc[mt][nt] = __builtin_amdgcn_mfma_f32_16x16x32_bf16(af[mt], bfrag[nt][kc], acc[mt][nt], 0, 0, 0);
    }
    __syncthreads();   // all Xs reads done

    // srcT tile (+bias) -> bf16 -> Xs (pair-packed via shfl_xor: 4B aligned writes, 2-way max)
#pragma unroll
    for (int mt = 0; mt < 4; ++mt) {
#pragma unroll
        for (int nt = 0; nt < 4; ++nt) {
            const int col = wn * 64 + nt * 16 + lm;
            const float bv = bt_src[r * 128 + col];
#pragma unroll
            for (int rg = 0; rg < 4; ++rg) {
                unsigned mb = f2bf(acc[mt][nt][rg] + bv);
                unsigned pb = (unsigned)__shfl_xor((int)mb, 1);
                if ((lm & 1) == 0) {
                    int trow = wm * 64 + mt * 16 + quad * 4 + rg;
                    *(unsigned*)(&Xs[trow * XPITCH + col]) = mb | (pb << 16);
                }
            }
        }
    }
    // preload B2 fragments (Wg^T) while stores drain
    const unsigned short* B2 = WgT + r * 16384;
#pragma unroll
    for (int nt = 0; nt < 4; ++nt)
#pragma unroll
        for (int kc = 0; kc < 4; ++kc)
            bfrag[nt][kc] = *(const short8*)(B2 + (wn * 64 + nt * 16 + lm) * 128 + kc * 32 + quad * 8);
    __syncthreads();

#pragma unroll
    for (int i = 0; i < 4; ++i)
#pragma unroll
        for (int j = 0; j < 4; ++j) acc[i][j] = (floatx4){0.f, 0.f, 0.f, 0.f};

    // GEMM2: hs tile
#pragma unroll
    for (int kc = 0; kc < 4; ++kc) {
        short8 af[4];
#pragma unroll
        for (int mt = 0; mt < 4; ++mt)
            af[mt] = *(const short8*)(&Xs[(wm * 64 + mt * 16 + lm) * XPITCH + kc * 32 + quad * 8]);
#pragma unroll
        for (int mt = 0; mt < 4; ++mt)
#pragma unroll
            for (int nt = 0; nt < 4; ++nt)
                acc[mt][nt] = __builtin_amdgcn_mfma_f32_16x16x32_bf16(af[mt], bfrag[nt][kc], acc[mt][nt], 0, 0, 0);
    }

    // epilogue: write hs + compute el[row][h] = sum_col hs*attn_l
    const float* alr = attn_l + r * 128;
    float* hsr = hs + (size_t)r * N_NODES * 128;
#pragma unroll
    for (int mt = 0; mt < 4; ++mt) {
        float eA[4] = {0.f, 0.f, 0.f, 0.f}, eB[4] = {0.f, 0.f, 0.f, 0.f};
#pragma unroll
        for (int nt = 0; nt < 4; ++nt) {
            const int col = wn * 64 + nt * 16 + lm;
            const float al = alr[col];
#pragma unroll
            for (int rg = 0; rg < 4; ++rg) {
                int gr = row0 + wm * 64 + mt * 16 + quad * 4 + rg;
                float v = acc[mt][nt][rg];
                if (gr < N_NODES) hsr[(size_t)gr * 128 + col] = v;
                float p = v * al;
                if (nt < 2) eA[rg] += p; else eB[rg] += p;
            }
        }
#pragma unroll
        for (int rg = 0; rg < 4; ++rg) {
            float a = eA[rg], b = eB[rg];
#pragma unroll
            for (int off = 8; off >= 1; off >>= 1) {
                a += __shfl_down(a, off);
                b += __shfl_down(b, off);
            }
            if (lm == 0) {
                int trow = wm * 64 + mt * 16 + quad * 4 + rg;
                els[trow][wn * 2 + 0] = a;
                els[trow][wn * 2 + 1] = b;
            }
        }
    }
    __syncthreads();
#pragma unroll
    for (int i = 0; i < 2; ++i) {
        int idx = t + i * 256;          // 512 = 128 x 4
        int trow = idx >> 2, h = idx & 3;
        int gr = row0 + trow;
        if (gr < N_NODES) el[((size_t)r * N_NODES + gr) * 4 + h] = els[trow][h];
    }
}

// ---------------- fused semantic: T=zr@W1+b1 (regs only) -> partial of sum(tanh(T)*W2) --------
__global__ __launch_bounds__(256) void fused_sem_kernel(
    const float* __restrict__ zr, const unsigned short* __restrict__ W1T,
    const float* __restrict__ b1, const float* __restrict__ W2,
    float* __restrict__ partials)
{
    __shared__ unsigned short Xs[128 * XPITCH];
    const int r = blockIdx.y;
    const int row0 = blockIdx.x * 128;
    const int t = threadIdx.x, wave = t >> 6, lane = t & 63;
    const int wm = wave >> 1, wn = wave & 1, lm = lane & 15, quad = lane >> 4;
    const float* A = zr + (size_t)r * N_NODES * 128;

#pragma unroll
    for (int i = 0; i < 16; ++i) {
        int item = t + i * 256;
        int m = item >> 5, kq = item & 31;
        int gr = row0 + m; gr = gr < N_NODES ? gr : N_NODES - 1;
        float4 v = *(const float4*)(A + (size_t)gr * 128 + kq * 4);
        uint2 u;
        u.x = f2bf(v.x) | (f2bf(v.y) << 16);
        u.y = f2bf(v.z) | (f2bf(v.w) << 16);
        *(uint2*)(&Xs[m * XPITCH + kq * 4]) = u;
    }
    short8 bfrag[4][4];
#pragma unroll
    for (int nt = 0; nt < 4; ++nt)
#pragma unroll
        for (int kc = 0; kc < 4; ++kc)
            bfrag[nt][kc] = *(const short8*)(W1T + (wn * 64 + nt * 16 + lm) * 128 + kc * 32 + quad * 8);
    __syncthreads();

    floatx4 acc[4][4];
#pragma unroll
    for (int i = 0; i < 4; ++i)
#pragma unroll
        for (int j = 0; j < 4; ++j) acc[i][j] = (floatx4){0.f, 0.f, 0.f, 0.f};
#pragma unroll
    for (int kc = 0; kc < 4; ++kc) {
        short8 af[4];
#pragma unroll
        for (int mt = 0; mt < 4; ++mt)
            af[mt] = *(const short8*)(&Xs[(wm * 64 + mt * 16 + lm) * XPITCH + kc * 32 + quad * 8]);
#pragma unroll
        for (int mt = 0; mt < 4; ++mt)
#pragma unroll
            for (int nt = 0; nt < 4; ++nt)
                acc[mt][nt] = __builtin_amdgcn_mfma_f32_16x16x32_bf16(af[mt], bfrag[nt][kc], acc[mt][nt], 0, 0, 0);
    }

    float s = 0.0f;
#pragma unroll
    for (int nt = 0; nt < 4; ++nt) {
        const int col = wn * 64 + nt * 16 + lm;
        const float w2v = W2[col];
        const float b1v = b1[col];
#pragma unroll
        for (int mt = 0; mt < 4; ++mt)
#pragma unroll
            for (int rg = 0; rg < 4; ++rg) {
                int gr = row0 + wm * 64 + mt * 16 + quad * 4 + rg;
                if (gr < N_NODES) s += fast_tanh(acc[mt][nt][rg] + b1v) * w2v;
            }
    }
#pragma unroll
    for (int off = 32; off >= 1; off >>= 1) s += __shfl_down(s, off);
    __shared__ float ws4[4];
    if (lane == 0) ws4[wave] = s;
    __syncthreads();
    if (t == 0) partials[r * GBLK + blockIdx.x] = ws4[0] + ws4[1] + ws4[2] + ws4[3];
}

// ---------------- CSR build ----------------
__global__ void count_kernel(const int* __restrict__ dst_idx, int* __restrict__ counts)
{
    int tid = blockIdx.x * 256 + threadIdx.x;
    if (tid >= R_REL * E_EDGES) return;
    int r = tid / E_EDGES;
    atomicAdd(&counts[r * N_NODES + dst_idx[tid]], 1);
}

__global__ void blocksum_kernel(const int* __restrict__ counts, int* __restrict__ bsums)
{
    int r = blockIdx.y;
    int i = blockIdx.x * 256 + threadIdx.x;
    int v = (i < N_NODES) ? counts[r * N_NODES + i] : 0;
#pragma unroll
    for (int off = 32; off >= 1; off >>= 1) v += __shfl_down(v, off);
    __shared__ int wsum[4];
    int lane = threadIdx.x & 63, w = threadIdx.x >> 6;
    if (lane == 0) wsum[w] = v;
    __syncthreads();
    if (threadIdx.x == 0) bsums[r * NBLK + blockIdx.x] = wsum[0] + wsum[1] + wsum[2] + wsum[3];
}

__global__ void scan_bsums(const int* __restrict__ bsums, int* __restrict__ boffs,
                           int* __restrict__ offs)
{
    int r = blockIdx.x;
    if (threadIdx.x != 0) return;
    int run = 0;
    for (int b = 0; b < NBLK; ++b) { boffs[r * NBLK + b] = run; run += bsums[r * NBLK + b]; }
    offs[r * (N_NODES + 1) + N_NODES] = run;
}

__global__ void scan_final(const int* __restrict__ counts, const int* __restrict__ boffs,
                           int* __restrict__ offs, int* __restrict__ cursor)
{
    int r = blockIdx.y;
    int i = blockIdx.x * 256 + threadIdx.x;
    int t = threadIdx.x;
    int v = (i < N_NODES) ? counts[r * N_NODES + i] : 0;
    __shared__ int sd[256];
    sd[t] = v;
    __syncthreads();
    for (int off = 1; off < 256; off <<= 1) {
        int y = (t >= off) ? sd[t - off] : 0;
        __syncthreads();
        sd[t] += y;
        __syncthreads();
    }
    int excl = sd[t] - v + boffs[r * NBLK + blockIdx.x];
    if (i < N_NODES) {
        offs[r * (N_NODES + 1) + i] = excl;
        cursor[r * N_NODES + i] = excl;
    }
}

// scatter + fused edge logits (softmax shift-invariance: no max subtraction needed, logits O(1))
__global__ void scatter_ex(const int* __restrict__ src_idx, const int* __restrict__ dst_idx,
                           const float* __restrict__ el, const float* __restrict__ er,
                           int* __restrict__ cursor, int* __restrict__ csr_src,
                           float* __restrict__ ex_csr)
{
    int tid = blockIdx.x * 256 + threadIdx.x;
    if (tid >= R_REL * E_EDGES) return;
    int r = tid / E_EDGES;
    int s = src_idx[tid], d = dst_idx[tid];
    float4 a = *(const float4*)(el + ((size_t)r * N_NODES + s) * 4);
    float4 b = *(const float4*)(er + ((size_t)r * N_NODES + d) * 4);
    float e0 = a.x + b.x, e1 = a.y + b.y, e2 = a.z + b.z, e3 = a.w + b.w;
    e0 = e0 > 0.f ? e0 : 0.2f * e0;
    e1 = e1 > 0.f ? e1 : 0.2f * e1;
    e2 = e2 > 0.f ? e2 : 0.2f * e2;
    e3 = e3 > 0.f ? e3 : 0.2f * e3;
    float4 ex = { __expf(e0), __expf(e1), __expf(e2), __expf(e3) };
    int pos = atomicAdd(&cursor[r * N_NODES + d], 1);
    csr_src[(size_t)r * E_EDGES + pos] = s;
    *(float4*)(ex_csr + ((size_t)r * E_EDGES + pos) * 4) = ex;
}

// ---------------- node-centric aggregation: one wave per (r,n), ILP-unrolled gathers ----------
__global__ __launch_bounds__(256) void agg_kernel(
    const float* __restrict__ ex_csr, const float* __restrict__ hs,
    const int* __restrict__ offs, const int* __restrict__ csr_src,
    const float* __restrict__ bias_g, float* __restrict__ zr)
{
    int wid = blockIdx.x * 4 + (threadIdx.x >> 6);
    int r = wid / N_NODES, n = wid - r * N_NODES;
    int lane = threadIdx.x & 63;
    int h0 = lane >> 5;
    int c0 = lane, c1 = lane + 64;

    int beg = offs[r * (N_NODES + 1) + n];
    int end = offs[r * (N_NODES + 1) + n + 1];
    const int*   srcs = csr_src + (size_t)r * E_EDGES;
    const float* exc  = ex_csr + (size_t)r * E_EDGES * 4;
    const float* hsr  = hs + (size_t)r * N_NODES * HD;

    float ss0 = 0.f, ss1 = 0.f, acc0 = 0.f, acc1 = 0.f;
    for (int base = beg; base < end; base += 64) {
        int j = base + lane;
        bool v = j < end;
        int jj = v ? j : base;
        int sv = srcs[jj];
        float4 exv = *(const float4*)(exc + (size_t)jj * 4);
        if (!v) { exv.x = 0.f; exv.y = 0.f; exv.z = 0.f; exv.w = 0.f; }
        int cnt4 = (min(64, end - base) + 3) & ~3;
        for (int k = 0; k < cnt4; k += 4) {
            int s0 = __shfl(sv, k),     s1 = __shfl(sv, k + 1);
            int s2 = __shfl(sv, k + 2), s3 = __shfl(sv, k + 3);
            float x0 = __shfl(exv.x, k), y0 = __shfl(exv.y, k), z0 = __shfl(exv.z, k), w0 = __shfl(exv.w, k);
            float x1 = __shfl(exv.x, k+1), y1 = __shfl(exv.y, k+1), z1 = __shfl(exv.z, k+1), w1 = __shfl(exv.w, k+1);
            float x2 = __shfl(exv.x, k+2), y2 = __shfl(exv.y, k+2), z2 = __shfl(exv.z, k+2), w2 = __shfl(exv.w, k+2);
            float x3 = __shfl(exv.x, k+3), y3 = __shfl(exv.y, k+3), z3 = __shfl(exv.z, k+3), w3 = __shfl(exv.w, k+3);
            float g00 = hsr[(size_t)s0 * HD + c0], g01 = hsr[(size_t)s0 * HD + c1];
            float g10 = hsr[(size_t)s1 * HD + c0], g11 = hsr[(size_t)s1 * HD + c1];
            float g20 = hsr[(size_t)s2 * HD + c0], g21 = hsr[(size_t)s2 * HD + c1];
            float g30 = hsr[(size_t)s3 * HD + c0], g31 = hsr[(size_t)s3 * HD + c1];
            float e00 = h0 ? y0 : x0, e10 = h0 ? w0 : z0;
            float e01 = h0 ? y1 : x1, e11 = h0 ? w1 : z1;
            float e02 = h0 ? y2 : x2, e12 = h0 ? w2 : z2;
            float e03 = h0 ? y3 : x3, e13 = h0 ? w3 : z3;
            ss0 += e00 + e01 + e02 + e03;
            ss1 += e10 + e11 + e12 + e13;
            acc0 += e00 * g00 + e01 * g10 + e02 * g20 + e03 * g30;
            acc1 += e10 * g01 + e11 * g11 + e12 * g21 + e13 * g31;
        }
    }
    float r0 = acc0 / (ss0 + 1e-9f) + bias_g[r * HD + c0];
    float r1 = acc1 / (ss1 + 1e-9f) + bias_g[r * HD + c1];
    r0 = r0 > 0.0f ? r0 : (__expf(r0) - 1.0f);
    r1 = r1 > 0.0f ? r1 : (__expf(r1) - 1.0f);
    zr[(size_t)wid * HD + c0] = r0;
    zr[(size_t)wid * HD + c1] = r1;
}

// ---------------- final softmax over relations + combine ----------------
__global__ __launch_bounds__(256) void softmax_a(const float* __restrict__ partials,
                                                 float* __restrict__ a,
                                                 float* __restrict__ out)
{
    __shared__ float sm[3];
    const int t = threadIdx.x;
    if (t < 192) {
        const int r = t >> 6, lane = t & 63;
        float v = 0.0f;
        for (int i = lane; i < GBLK; i += 64) v += partials[r * GBLK + i];
#pragma unroll
        for (int off = 32; off >= 1; off >>= 1) v += __shfl_down(v, off);
        if (lane == 0) sm[r] = v;
    }
    __syncthreads();
    if (t == 0) {
        float w0 = sm[0] / (float)N_NODES;
        float w1 = sm[1] / (float)N_NODES;
        float w2 = sm[2] / (float)N_NODES;
        float m = fmaxf(w0, fmaxf(w1, w2));
        float e0 = __expf(w0 - m), e1 = __expf(w1 - m), e2 = __expf(w2 - m);
        float s = e0 + e1 + e2;
        a[0] = e0 / s; a[1] = e1 / s; a[2] = e2 / s;
        out[(size_t)N_NODES * HD + 0] = a[0];
        out[(size_t)N_NODES * HD + 1] = a[1];
        out[(size_t)N_NODES * HD + 2] = a[2];
    }
}

__global__ __launch_bounds__(256) void combine_kernel(const float* __restrict__ zr,
                                                      const float* __restrict__ a,
                                                      float* __restrict__ out)
{
    size_t i = (size_t)blockIdx.x * 256 + threadIdx.x;
    float a0 = a[0], a1 = a[1], a2 = a[2];
    const float4 v0 = ((const float4*)zr)[i];
    const float4 v1 = ((const float4*)(zr + (size_t)N_NODES * HD))[i];
    const float4 v2 = ((const float4*)(zr + 2 * (size_t)N_NODES * HD))[i];
    float4 o = { a0 * v0.x + a1 * v1.x + a2 * v2.x,
                 a0 * v0.y + a1 * v1.y + a2 * v2.y,
                 a0 * v0.z + a1 * v1.z + a2 * v2.z,
                 a0 * v0.w + a1 * v1.w + a2 * v2.w };
    ((float4*)out)[i] = o;
}

// ---------------- launch ----------------
extern "C" void kernel_launch(void* const* d_in, const int* in_sizes, int n_in,
                              void* d_out, int out_size, void* d_ws, size_t ws_size,
                              hipStream_t stream)
{
    const float* dst_feat  = (const float*)d_in[0];
    const float* src_feats = (const float*)d_in[1];
    const int*   src_idx   = (const int*)d_in[2];
    const int*   dst_idx   = (const int*)d_in[3];
    const float* Wt_dst    = (const float*)d_in[4];
    const float* bt_dst    = (const float*)d_in[5];
    const float* Wt_src    = (const float*)d_in[6];
    const float* bt_src    = (const float*)d_in[7];
    const float* Wg        = (const float*)d_in[8];
    const float* attn_l    = (const float*)d_in[9];
    const float* attn_r    = (const float*)d_in[10];
    const float* bias_g    = (const float*)d_in[11];
    const float* W1        = (const float*)d_in[12];
    const float* b1        = (const float*)d_in[13];
    const float* W2        = (const float*)d_in[14];
    float* out = (float*)d_out;

    char* ws = (char*)d_ws;
    float*          ex_csr = (float*)(ws + OFF_EXCSR);
    unsigned short* WtsT   = (unsigned short*)(ws + OFF_WTS_T);
    unsigned short* WgT    = (unsigned short*)(ws + OFF_WG_T);
    unsigned short* W1T    = (unsigned short*)(ws + OFF_W1_T);
    float*          Mer    = (float*)(ws + OFF_MER);
    float*          cer    = (float*)(ws + OFF_CER);
    float*          parts  = (float*)(ws + OFF_PART);
    float*          zr     = (float*)(ws + OFF_B1);
    float*          hs     = (float*)(ws + OFF_B2);
    float*          el     = (float*)(ws + OFF_EL);
    float*          er     = (float*)(ws + OFF_ER);
    int*            counts = (int*)(ws + OFF_CNT);
    int*            offs   = (int*)(ws + OFF_OFFS);
    int*            cursor = (int*)(ws + OFF_CUR);
    int*            bsums  = (int*)(ws + OFF_BSUM);
    int*            boffs  = (int*)(ws + OFF_BOFF);
    int*            csr    = (int*)(ws + OFF_CSR);
    float*          abuf   = (float*)(ws + OFF_ABUF);

    hipMemsetAsync(counts, 0, (size_t)R_REL * N_NODES * 4, stream);

    // prep: weight transposes (bf16 [n][k]) + er projection matrix
    transpose_bf16<<<dim3(64, 3), 256, 0, stream>>>(Wt_src, WtsT);
    transpose_bf16<<<dim3(64, 3), 256, 0, stream>>>(Wg, WgT);
    transpose_bf16<<<dim3(64, 1), 256, 0, stream>>>(W1, W1T);
    prep_er<<<3, 512, 0, stream>>>(Wg, attn_r, Wt_dst, bt_dst, Mer, cer);

    // fused src projection chain: hs + el (srcT never touches HBM)
    fused_src_kernel<<<dim3(GBLK, 3), 256, 0, stream>>>(src_feats, WtsT, bt_src, WgT,
                                                        attn_l, hs, el);
    // er directly from dst_feat
    er_direct<<<25000, 256, 0, stream>>>(dst_feat, Mer, cer, er);

    // CSR by dst
    count_kernel<<<3750, 256, 0, stream>>>(dst_idx, counts);
    blocksum_kernel<<<dim3(NBLK, 3), 256, 0, stream>>>(counts, bsums);
    scan_bsums<<<3, 64, 0, stream>>>(bsums, boffs, offs);
    scan_final<<<dim3(NBLK, 3), 256, 0, stream>>>(counts, boffs, offs, cursor);
    scatter_ex<<<3750, 256, 0, stream>>>(src_idx, dst_idx, el, er, cursor, csr, ex_csr);

    // pull aggregation -> zr
    agg_kernel<<<75000, 256, 0, stream>>>(ex_csr, hs, offs, csr, bias_g, zr);

    // fused semantic attention (T never materialized)
    fused_sem_kernel<<<dim3(GBLK, 3), 256, 0, stream>>>(zr, W1T, b1, W2, parts);
    softmax_a<<<1, 256, 0, stream>>>(parts, abuf, out);
    combine_kernel<<<12500, 256, 0, stream>>>(zr, abuf, out);
}